// Round 2
// baseline (29218.988 us; speedup 1.0000x reference)
//
#include <hip/hip_runtime.h>
#include <stdint.h>

// SR-GNN fused kernel: one workgroup per batch element, 2 GRU steps + attention
// readout, single launch. Activations staged in LDS as bf16, fp32 accumulation,
// weights read as wave-uniform scalar loads (64-way lane broadcast reuse).
// R1 fix: hreg/sreg sized 64 uint32 (128 bf16 per row), was 32 -> OOB garbage -> NaN.

#define BDIM 256
#define NB   1024
#define NN   64
#define HH   128

__device__ __forceinline__ float b2f_lo(uint32_t u){
  union { uint32_t u; float f; } v; v.u = u << 16; return v.f;
}
__device__ __forceinline__ float b2f_hi(uint32_t u){
  union { uint32_t u; float f; } v; v.u = u & 0xffff0000u; return v.f;
}
__device__ __forceinline__ uint16_t f2b(float f){
  union { float f; uint32_t u; } v; v.f = f;
  uint32_t r = v.u + 0x7fffu + ((v.u >> 16) & 1u);   // RNE
  return (uint16_t)(r >> 16);
}
__device__ __forceinline__ float b2f(uint16_t s){
  union { uint32_t u; float f; } v; v.u = ((uint32_t)s) << 16; return v.f;
}
__device__ __forceinline__ float sig_f(float x){
  return 1.0f / (1.0f + __expf(-x));
}
__device__ __forceinline__ float tanh_f(float x){
  return 1.0f - 2.0f / (__expf(2.0f * x) + 1.0f);
}

__global__ __launch_bounds__(BDIM, 2) void srgnn_kernel(
    const float* __restrict__ A,
    const int*   __restrict__ items,
    const int*   __restrict__ mask,
    const int*   __restrict__ alias_input,
    const float* __restrict__ emb,
    const float* __restrict__ w_in,  const float* __restrict__ b_in,
    const float* __restrict__ w_out, const float* __restrict__ b_out,
    const float* __restrict__ b_iah, const float* __restrict__ b_oah,
    const float* __restrict__ wi,    const float* __restrict__ bi,
    const float* __restrict__ wh,    const float* __restrict__ bh,
    const float* __restrict__ w1,    const float* __restrict__ b1,
    const float* __restrict__ w2,    const float* __restrict__ b2,
    const float* __restrict__ wq,
    const float* __restrict__ w3,    const float* __restrict__ b3,
    float* __restrict__ out)
{
  // strides in ushorts; rows 16B-aligned (272B / 528B)
  constexpr int SH_STR = 136;   // 128 + 8 pad
  constexpr int SX_STR = 264;   // 256 + 8 pad
  __shared__ __align__(16) uint16_t sH[NN * SH_STR];   // hidden (bf16)
  __shared__ __align__(16) uint16_t sX[NN * SX_STR];   // h_in|h_out -> ie (bf16)
  __shared__ float sQ1[HH];
  __shared__ float sGlob[HH];
  __shared__ float sAPart[4][64];
  __shared__ float sAlpha[64];
  __shared__ int   sAliasRow[64];
  __shared__ int   sMaskArr[64];

  const int t    = threadIdx.x;
  const int b    = blockIdx.x;
  const int lane = t & 63;
  const int wv   = __builtin_amdgcn_readfirstlane(t >> 6);  // wave id, provably uniform

  // ---------- P0: hidden = emb[items[b]]  +  alias/mask staging ----------
  {
    const int* itb = items + b * NN;
    for (int j = t; j < NN * HH; j += BDIM) {
      int n = j >> 7, k = j & 127;
      int it = itb[n];
      sH[n * SH_STR + k] = f2b(emb[(size_t)it * HH + k]);
    }
    if (t < 64) {
      sAliasRow[t] = alias_input[b * 64 + t];
      sMaskArr[t]  = mask[b * 64 + t];
    }
  }
  __syncthreads();

  uint32_t hreg[64];   // lane's hidden row: 128 bf16 = 64 packed dwords (P1 & P3)

  for (int step = 0; step < 2; ++step) {
    // ---------- P1: sX[n][c] = bias[c] + sum_k hidden[n][k] * w[c][k] ----------
    {
      const uint4* src = reinterpret_cast<const uint4*>(&sH[lane * SH_STR]);
      #pragma unroll
      for (int i = 0; i < 16; ++i) {
        uint4 v = src[i];
        hreg[4*i+0] = v.x; hreg[4*i+1] = v.y; hreg[4*i+2] = v.z; hreg[4*i+3] = v.w;
      }
    }
    {
      const bool isIn   = (wv < 2);
      const float* wsel = isIn ? w_in : w_out;
      const float* bsel = isIn ? b_in : b_out;
      #pragma unroll 1
      for (int i = 0; i < 64; ++i) {
        int col = wv * 64 + i;                 // 0..255 column of sX
        int c0  = isIn ? col : col - 128;      // row of w_in / w_out
        const float* wr = wsel + c0 * HH;      // wave-uniform -> s_load
        float a0 = bsel[c0], a1 = 0.0f;
        #pragma unroll
        for (int kp = 0; kp < 64; ++kp) {
          uint32_t u = hreg[kp];
          a0 = fmaf(b2f_lo(u), wr[2*kp],   a0);
          a1 = fmaf(b2f_hi(u), wr[2*kp+1], a1);
        }
        sX[lane * SX_STR + col] = f2b(a0 + a1);
      }
    }
    __syncthreads();

    // ---------- P2: ie = A_in @ h_in | A_out @ h_out, in place over sX ----------
    // Each wave owns a disjoint set of columns; within a wave all column reads
    // precede the store in program order (lockstep) -> in-place is safe.
    {
      const float* Ab = A + ((size_t)b * NN + lane) * (2 * NN);
      float areg[64];
      // P2a: columns 0..127 use A[:, :, 0:64] and h_in
      #pragma unroll
      for (int m = 0; m < 64; ++m) areg[m] = Ab[m];
      #pragma unroll 1
      for (int i = 0; i < 32; ++i) {
        int tc = wv * 32 + i;
        float c0 = b_iah[tc], c1 = 0.f, c2 = 0.f, c3 = 0.f;
        #pragma unroll
        for (int m = 0; m < 64; m += 4) {
          c0 = fmaf(areg[m+0], b2f(sX[(m+0) * SX_STR + tc]), c0);
          c1 = fmaf(areg[m+1], b2f(sX[(m+1) * SX_STR + tc]), c1);
          c2 = fmaf(areg[m+2], b2f(sX[(m+2) * SX_STR + tc]), c2);
          c3 = fmaf(areg[m+3], b2f(sX[(m+3) * SX_STR + tc]), c3);
        }
        sX[lane * SX_STR + tc] = f2b((c0 + c1) + (c2 + c3));
      }
      // P2b: columns 128..255 use A[:, :, 64:128] and h_out
      #pragma unroll
      for (int m = 0; m < 64; ++m) areg[m] = Ab[64 + m];
      #pragma unroll 1
      for (int i = 0; i < 32; ++i) {
        int tc = 128 + wv * 32 + i;
        float c0 = b_oah[tc - 128], c1 = 0.f, c2 = 0.f, c3 = 0.f;
        #pragma unroll
        for (int m = 0; m < 64; m += 4) {
          c0 = fmaf(areg[m+0], b2f(sX[(m+0) * SX_STR + tc]), c0);
          c1 = fmaf(areg[m+1], b2f(sX[(m+1) * SX_STR + tc]), c1);
          c2 = fmaf(areg[m+2], b2f(sX[(m+2) * SX_STR + tc]), c2);
          c3 = fmaf(areg[m+3], b2f(sX[(m+3) * SX_STR + tc]), c3);
        }
        sX[lane * SX_STR + tc] = f2b((c0 + c1) + (c2 + c3));
      }
    }
    __syncthreads();

    // ---------- P3: gates; writes new hidden into sH ----------
    {
      uint32_t iereg[128];   // lane's ie row (256 bf16), packed
      const uint4* src = reinterpret_cast<const uint4*>(&sX[lane * SX_STR]);
      #pragma unroll
      for (int i = 0; i < 32; ++i) {
        uint4 v = src[i];
        iereg[4*i+0] = v.x; iereg[4*i+1] = v.y; iereg[4*i+2] = v.z; iereg[4*i+3] = v.w;
      }
      __syncthreads();   // all waves finished caching sX before overwrite phase

      #pragma unroll 1
      for (int i = 0; i < 32; ++i) {
        int h = wv * 32 + i;
        const float* wiR = wi + (size_t)h * 256;
        const float* wiI = wi + (size_t)(h + 128) * 256;
        const float* wiN = wi + (size_t)(h + 256) * 256;
        const float* whR = wh + (size_t)h * 128;
        const float* whI = wh + (size_t)(h + 128) * 128;
        const float* whN = wh + (size_t)(h + 256) * 128;
        float ir = bi[h], ii = bi[h + 128], inn = bi[h + 256];
        float hr = bh[h], hi = bh[h + 128], hn = bh[h + 256];
        #pragma unroll
        for (int cp = 0; cp < 128; ++cp) {
          uint32_t u = iereg[cp];
          float lo = b2f_lo(u), hi2 = b2f_hi(u);
          ir  = fmaf(lo, wiR[2*cp],   ir);  ir  = fmaf(hi2, wiR[2*cp+1], ir);
          ii  = fmaf(lo, wiI[2*cp],   ii);  ii  = fmaf(hi2, wiI[2*cp+1], ii);
          inn = fmaf(lo, wiN[2*cp],   inn); inn = fmaf(hi2, wiN[2*cp+1], inn);
        }
        #pragma unroll
        for (int kp = 0; kp < 64; ++kp) {
          uint32_t u = hreg[kp];
          float lo = b2f_lo(u), hi2 = b2f_hi(u);
          hr = fmaf(lo, whR[2*kp],   hr); hr = fmaf(hi2, whR[2*kp+1], hr);
          hi = fmaf(lo, whI[2*kp],   hi); hi = fmaf(hi2, whI[2*kp+1], hi);
          hn = fmaf(lo, whN[2*kp],   hn); hn = fmaf(hi2, whN[2*kp+1], hn);
        }
        float z = sig_f(ii + hi);
        float r = sig_f(ir + hr);
        float g = tanh_f(fmaf(r, hn, inn));
        float hprev = b2f(sH[lane * SH_STR + h]);      // read before write, same thread
        float nh = fmaf(z, g - hprev, hprev);          // (1-z)h + z*g
        sH[lane * SH_STR + h] = f2b(nh);
      }
    }
    __syncthreads();
  }

  // ---------- P4: attention readout ----------
  int msum = 0;
  #pragma unroll
  for (int l = 0; l < 64; ++l) msum += sMaskArr[l];
  const int lastRow = sAliasRow[msum - 1];

  // q1[h] = b1[h] + sum_k local[k] * w1[h][k]
  if (t < HH) {
    const float* w1r = w1 + t * HH;
    float a0 = b1[t], a1 = 0.0f;
    #pragma unroll
    for (int k = 0; k < HH; k += 2) {
      a0 = fmaf(b2f(sH[lastRow * SH_STR + k]),     w1r[k],   a0);
      a1 = fmaf(b2f(sH[lastRow * SH_STR + k + 1]), w1r[k+1], a1);
    }
    sQ1[t] = a0 + a1;
  }
  __syncthreads();

  // alpha partials: lane = l, wave covers h in [wv*32, wv*32+32)
  {
    uint32_t sreg[64];   // seq_hidden row: 128 bf16 = 64 packed dwords
    const int myrow = sAliasRow[lane];
    const uint4* src = reinterpret_cast<const uint4*>(&sH[myrow * SH_STR]);
    #pragma unroll
    for (int i = 0; i < 16; ++i) {
      uint4 v = src[i];
      sreg[4*i+0] = v.x; sreg[4*i+1] = v.y; sreg[4*i+2] = v.z; sreg[4*i+3] = v.w;
    }
    float apart = 0.0f;
    #pragma unroll 1
    for (int i = 0; i < 32; ++i) {
      int h = wv * 32 + i;
      const float* w2r = w2 + h * HH;       // wave-uniform -> s_load
      float a0 = b2[h], a1 = 0.0f;
      #pragma unroll
      for (int kp = 0; kp < 64; ++kp) {
        uint32_t u = sreg[kp];
        a0 = fmaf(b2f_lo(u), w2r[2*kp],   a0);
        a1 = fmaf(b2f_hi(u), w2r[2*kp+1], a1);
      }
      apart += sig_f(sQ1[h] + (a0 + a1)) * wq[h];
    }
    sAPart[wv][lane] = apart;
  }
  __syncthreads();
  if (t < 64) {
    float a = sAPart[0][t] + sAPart[1][t] + sAPart[2][t] + sAPart[3][t];
    sAlpha[t] = a * (float)sMaskArr[t];
  }
  __syncthreads();
  // global_emb[h] = sum_l alpha[l] * seq_hidden[l][h]
  if (t < HH) {
    float acc = 0.0f;
    #pragma unroll
    for (int l = 0; l < 64; ++l) {
      int r = sAliasRow[l];
      acc = fmaf(sAlpha[l], b2f(sH[r * SH_STR + t]), acc);
    }
    sGlob[t] = acc;
  }
  __syncthreads();
  // out[h] = b3[h] + sum_k local[k]*w3[h][k] + sum_k glob[k]*w3[h][128+k]
  if (t < HH) {
    const float* w3r = w3 + t * 256;
    float a0 = b3[t], a1 = 0.0f;
    #pragma unroll
    for (int k = 0; k < HH; ++k) {
      a0 = fmaf(b2f(sH[lastRow * SH_STR + k]), w3r[k],      a0);
      a1 = fmaf(sGlob[k],                      w3r[HH + k], a1);
    }
    out[b * HH + t] = a0 + a1;
  }
}

extern "C" void kernel_launch(void* const* d_in, const int* in_sizes, int n_in,
                              void* d_out, int out_size, void* d_ws, size_t ws_size,
                              hipStream_t stream) {
  const float* A          = (const float*)d_in[0];
  const int*   items      = (const int*)  d_in[1];
  const int*   mask       = (const int*)  d_in[2];
  const int*   alias_in   = (const int*)  d_in[3];
  const float* emb        = (const float*)d_in[4];
  const float* w_in       = (const float*)d_in[5];
  const float* b_in       = (const float*)d_in[6];
  const float* w_out      = (const float*)d_in[7];
  const float* b_out      = (const float*)d_in[8];
  const float* b_iah      = (const float*)d_in[9];
  const float* b_oah      = (const float*)d_in[10];
  const float* wi         = (const float*)d_in[11];
  const float* bi         = (const float*)d_in[12];
  const float* wh         = (const float*)d_in[13];
  const float* bh         = (const float*)d_in[14];
  const float* w1         = (const float*)d_in[15];
  const float* b1         = (const float*)d_in[16];
  const float* w2         = (const float*)d_in[17];
  const float* b2         = (const float*)d_in[18];
  const float* wq         = (const float*)d_in[19];
  const float* w3         = (const float*)d_in[20];
  const float* b3         = (const float*)d_in[21];
  float* out = (float*)d_out;

  hipLaunchKernelGGL(srgnn_kernel, dim3(NB), dim3(BDIM), 0, stream,
                     A, items, mask, alias_in, emb,
                     w_in, b_in, w_out, b_out, b_iah, b_oah,
                     wi, bi, wh, bh, w1, b1, w2, b2, wq, w3, b3, out);
}

// Round 3
// 28701.743 us; speedup vs baseline: 1.0180x; 1.0180x over previous
//
#include <hip/hip_runtime.h>
#include <stdint.h>

// SR-GNN fused kernel: one workgroup per batch element, 2 GRU steps + attention
// readout, single launch. Activations in LDS as bf16, fp32 accumulation,
// weights via wave-uniform loads (L2-resident, 64-lane broadcast).
// R2 fix: removed iereg[128]/areg-wide register caches that spilled to scratch
// (WRITE_SIZE showed 2 GB of spill traffic); inner loops now read LDS directly.
// Only P3 keeps a 64-dword snapshot of the hidden row (race-safety + fits regs).

#define BDIM 256
#define NB   1024
#define NN   64
#define HH   128

// LDS row strides (uint16 units). Rows 8B-aligned; dword stride % 32 kept
// small-factor: sH 66 dwords (2-lane/bank), sX 134 dwords (4-way worst).
#define SH_STR 132
#define SX_STR 268

__device__ __forceinline__ float b2f_lo(uint32_t u){
  union { uint32_t u; float f; } v; v.u = u << 16; return v.f;
}
__device__ __forceinline__ float b2f_hi(uint32_t u){
  union { uint32_t u; float f; } v; v.u = u & 0xffff0000u; return v.f;
}
__device__ __forceinline__ uint16_t f2b(float f){
  union { float f; uint32_t u; } v; v.f = f;
  uint32_t r = v.u + 0x7fffu + ((v.u >> 16) & 1u);   // RNE
  return (uint16_t)(r >> 16);
}
__device__ __forceinline__ float b2f(uint16_t s){
  union { uint32_t u; float f; } v; v.u = ((uint32_t)s) << 16; return v.f;
}
__device__ __forceinline__ float sig_f(float x){
  return 1.0f / (1.0f + __expf(-x));
}
__device__ __forceinline__ float tanh_f(float x){
  return 1.0f - 2.0f / (__expf(2.0f * x) + 1.0f);
}

__global__ __launch_bounds__(BDIM, 3) void srgnn_kernel(
    const float* __restrict__ A,
    const int*   __restrict__ items,
    const int*   __restrict__ mask,
    const int*   __restrict__ alias_input,
    const float* __restrict__ emb,
    const float* __restrict__ w_in,  const float* __restrict__ b_in,
    const float* __restrict__ w_out, const float* __restrict__ b_out,
    const float* __restrict__ b_iah, const float* __restrict__ b_oah,
    const float* __restrict__ wi,    const float* __restrict__ bi,
    const float* __restrict__ wh,    const float* __restrict__ bh,
    const float* __restrict__ w1,    const float* __restrict__ b1,
    const float* __restrict__ w2,    const float* __restrict__ b2,
    const float* __restrict__ wq,
    const float* __restrict__ w3,    const float* __restrict__ b3,
    float* __restrict__ out)
{
  __shared__ __align__(16) uint16_t sH[NN * SH_STR];   // hidden (bf16), 16.9 KB
  __shared__ __align__(16) uint16_t sX[NN * SX_STR];   // h_in|h_out -> ie, 34.3 KB
  __shared__ int sAliasRow[64];
  __shared__ int sMaskArr[64];
  // P4 scratch aliased into sX (sX dead after last P3)
  float* sQ1   = reinterpret_cast<float*>(sX);         // [128]
  float* sGlob = reinterpret_cast<float*>(sX) + 128;   // [128]
  float* sAPart= reinterpret_cast<float*>(sX) + 256;   // [4][64]
  float* sAlpha= reinterpret_cast<float*>(sX) + 512;   // [64]

  const int t    = threadIdx.x;
  const int b    = blockIdx.x;
  const int lane = t & 63;
  const int wv   = __builtin_amdgcn_readfirstlane(t >> 6);

  // ---------- P0: hidden = emb[items[b]]; alias/mask staging ----------
  {
    const int* itb = items + b * NN;
    for (int j = t; j < NN * HH; j += BDIM) {
      int n = j >> 7, k = j & 127;
      int it = itb[n];
      sH[n * SH_STR + k] = f2b(emb[(size_t)it * HH + k]);
    }
    if (t < 64) {
      sAliasRow[t] = alias_input[b * 64 + t];
      sMaskArr[t]  = mask[b * 64 + t];
    }
  }
  __syncthreads();

  for (int step = 0; step < 2; ++step) {
    // ---------- P1: sX[n][c] = bias[c] + sum_k h[n][k] * w[c][k] ----------
    {
      const bool isIn   = (wv < 2);
      const float* wsel = isIn ? w_in : w_out;
      const float* bsel = isIn ? b_in : b_out;
      const uint2* hrow = reinterpret_cast<const uint2*>(&sH[lane * SH_STR]);
      #pragma unroll 1
      for (int i = 0; i < 64; ++i) {
        int col = wv * 64 + i;
        int c0  = isIn ? col : col - 128;
        const float* wr = wsel + c0 * HH;      // wave-uniform
        float a0 = bsel[c0], a1 = 0.f, a2 = 0.f, a3 = 0.f;
        #pragma unroll
        for (int j = 0; j < 32; ++j) {
          uint2 v = hrow[j];                   // 4 bf16 of own hidden row
          a0 = fmaf(b2f_lo(v.x), wr[4*j+0], a0);
          a1 = fmaf(b2f_hi(v.x), wr[4*j+1], a1);
          a2 = fmaf(b2f_lo(v.y), wr[4*j+2], a2);
          a3 = fmaf(b2f_hi(v.y), wr[4*j+3], a3);
        }
        sX[lane * SX_STR + col] = f2b((a0 + a1) + (a2 + a3));
      }
    }
    __syncthreads();

    // ---------- P2: ie = A_in @ h_in | A_out @ h_out, in place over sX ----
    // Wave w reads/writes ONLY its own column range (broadcast reads of its
    // own cols, write to own row) -> disjoint across waves, in-place safe.
    {
      const float* Ab = A + ((size_t)b * NN + lane) * (2 * NN);
      float areg[64];
      // P2a: cols [wv*32, wv*32+32) use A[:, :, 0:64]
      #pragma unroll
      for (int m = 0; m < 64; ++m) areg[m] = Ab[m];
      #pragma unroll 1
      for (int i = 0; i < 16; ++i) {
        int cc = wv * 32 + 2 * i;
        float e0 = b_iah[cc], e1 = 0.f, o0 = b_iah[cc + 1], o1 = 0.f;
        #pragma unroll
        for (int m = 0; m < 64; m += 2) {
          uint32_t u0 = *reinterpret_cast<const uint32_t*>(&sX[(m+0) * SX_STR + cc]);
          uint32_t u1 = *reinterpret_cast<const uint32_t*>(&sX[(m+1) * SX_STR + cc]);
          e0 = fmaf(areg[m+0], b2f_lo(u0), e0);
          o0 = fmaf(areg[m+0], b2f_hi(u0), o0);
          e1 = fmaf(areg[m+1], b2f_lo(u1), e1);
          o1 = fmaf(areg[m+1], b2f_hi(u1), o1);
        }
        uint32_t w = (uint32_t)f2b(e0 + e1) | ((uint32_t)f2b(o0 + o1) << 16);
        *reinterpret_cast<uint32_t*>(&sX[lane * SX_STR + cc]) = w;
      }
      // P2b: cols [128+wv*32, ...) use A[:, :, 64:128]
      #pragma unroll
      for (int m = 0; m < 64; ++m) areg[m] = Ab[64 + m];
      #pragma unroll 1
      for (int i = 0; i < 16; ++i) {
        int cc = 128 + wv * 32 + 2 * i;
        float e0 = b_oah[cc - 128], e1 = 0.f, o0 = b_oah[cc - 127], o1 = 0.f;
        #pragma unroll
        for (int m = 0; m < 64; m += 2) {
          uint32_t u0 = *reinterpret_cast<const uint32_t*>(&sX[(m+0) * SX_STR + cc]);
          uint32_t u1 = *reinterpret_cast<const uint32_t*>(&sX[(m+1) * SX_STR + cc]);
          e0 = fmaf(areg[m+0], b2f_lo(u0), e0);
          o0 = fmaf(areg[m+0], b2f_hi(u0), o0);
          e1 = fmaf(areg[m+1], b2f_lo(u1), e1);
          o1 = fmaf(areg[m+1], b2f_hi(u1), o1);
        }
        uint32_t w = (uint32_t)f2b(e0 + e1) | ((uint32_t)f2b(o0 + o1) << 16);
        *reinterpret_cast<uint32_t*>(&sX[lane * SX_STR + cc]) = w;
      }
    }
    __syncthreads();

    // ---------- P3: gates; writes new hidden into sH ----------
    {
      // snapshot own hidden row (pre-update) — 64 packed dwords
      uint32_t hreg[64];
      {
        const uint2* hrow = reinterpret_cast<const uint2*>(&sH[lane * SH_STR]);
        #pragma unroll
        for (int j = 0; j < 32; ++j) { uint2 v = hrow[j]; hreg[2*j] = v.x; hreg[2*j+1] = v.y; }
      }
      __syncthreads();   // all snapshots done before any sH overwrite

      const uint2* xrow = reinterpret_cast<const uint2*>(&sX[lane * SX_STR]);
      #pragma unroll 1
      for (int i = 0; i < 32; ++i) {
        int h = wv * 32 + i;
        const float* wiR = wi + (size_t)h * 256;
        const float* wiI = wi + (size_t)(h + 128) * 256;
        const float* wiN = wi + (size_t)(h + 256) * 256;
        const float* whR = wh + (size_t)h * 128;
        const float* whI = wh + (size_t)(h + 128) * 128;
        const float* whN = wh + (size_t)(h + 256) * 128;
        float ir = bi[h], ii = bi[h + 128], inn = bi[h + 256];
        float hr = bh[h], hi = bh[h + 128], hn = bh[h + 256];
        #pragma unroll
        for (int j = 0; j < 64; ++j) {        // ie row: 256 bf16 via uint2
          uint2 v = xrow[j];
          float f0 = b2f_lo(v.x), f1 = b2f_hi(v.x);
          float f2 = b2f_lo(v.y), f3 = b2f_hi(v.y);
          ir  = fmaf(f0, wiR[4*j+0], ir);  ir  = fmaf(f1, wiR[4*j+1], ir);
          ir  = fmaf(f2, wiR[4*j+2], ir);  ir  = fmaf(f3, wiR[4*j+3], ir);
          ii  = fmaf(f0, wiI[4*j+0], ii);  ii  = fmaf(f1, wiI[4*j+1], ii);
          ii  = fmaf(f2, wiI[4*j+2], ii);  ii  = fmaf(f3, wiI[4*j+3], ii);
          inn = fmaf(f0, wiN[4*j+0], inn); inn = fmaf(f1, wiN[4*j+1], inn);
          inn = fmaf(f2, wiN[4*j+2], inn); inn = fmaf(f3, wiN[4*j+3], inn);
        }
        #pragma unroll
        for (int kp = 0; kp < 64; ++kp) {     // hidden row from snapshot
          uint32_t u = hreg[kp];
          float lo = b2f_lo(u), hi2 = b2f_hi(u);
          hr = fmaf(lo, whR[2*kp], hr); hr = fmaf(hi2, whR[2*kp+1], hr);
          hi = fmaf(lo, whI[2*kp], hi); hi = fmaf(hi2, whI[2*kp+1], hi);
          hn = fmaf(lo, whN[2*kp], hn); hn = fmaf(hi2, whN[2*kp+1], hn);
        }
        float z = sig_f(ii + hi);
        float r = sig_f(ir + hr);
        float g = tanh_f(fmaf(r, hn, inn));
        float hprev = b2f_lo(hreg[h >> 1]);   // placeholder, replaced below
        // hprev from snapshot: dword h/2, parity h&1
        hprev = (h & 1) ? b2f_hi(hreg[h >> 1]) : b2f_lo(hreg[h >> 1]);
        float nh = fmaf(z, g - hprev, hprev);
        sH[lane * SH_STR + h] = f2b(nh);      // own (row,h) slot — no reader
      }
    }
    __syncthreads();
  }

  // ---------- P4: attention readout ----------
  int msum = 0;
  #pragma unroll
  for (int l = 0; l < 64; ++l) msum += sMaskArr[l];
  const int lastRow = sAliasRow[msum - 1];

  // q1[h] = b1[h] + dot(local, w1[h]) ; sQ1 aliases sX (sX is dead now)
  if (t < HH) {
    const float* w1r = w1 + t * HH;
    const uint2* lrow = reinterpret_cast<const uint2*>(&sH[lastRow * SH_STR]);
    float a0 = b1[t], a1 = 0.f, a2 = 0.f, a3 = 0.f;
    #pragma unroll
    for (int j = 0; j < 32; ++j) {
      uint2 v = lrow[j];
      a0 = fmaf(b2f_lo(v.x), w1r[4*j+0], a0);
      a1 = fmaf(b2f_hi(v.x), w1r[4*j+1], a1);
      a2 = fmaf(b2f_lo(v.y), w1r[4*j+2], a2);
      a3 = fmaf(b2f_hi(v.y), w1r[4*j+3], a3);
    }
    sQ1[t] = (a0 + a1) + (a2 + a3);
  }
  __syncthreads();

  // alpha partials: lane = l, wave covers h in [wv*32, wv*32+32)
  {
    const int myrow = sAliasRow[lane];
    const uint2* srow = reinterpret_cast<const uint2*>(&sH[myrow * SH_STR]);
    float apart = 0.0f;
    #pragma unroll 1
    for (int i = 0; i < 32; ++i) {
      int h = wv * 32 + i;
      const float* w2r = w2 + h * HH;        // wave-uniform
      float a0 = b2[h], a1 = 0.f, a2 = 0.f, a3 = 0.f;
      #pragma unroll
      for (int j = 0; j < 32; ++j) {
        uint2 v = srow[j];
        a0 = fmaf(b2f_lo(v.x), w2r[4*j+0], a0);
        a1 = fmaf(b2f_hi(v.x), w2r[4*j+1], a1);
        a2 = fmaf(b2f_lo(v.y), w2r[4*j+2], a2);
        a3 = fmaf(b2f_hi(v.y), w2r[4*j+3], a3);
      }
      apart += sig_f(sQ1[h] + (a0 + a1) + (a2 + a3)) * wq[h];
    }
    sAPart[wv * 64 + lane] = apart;
  }
  __syncthreads();
  if (t < 64) {
    float a = sAPart[0*64+t] + sAPart[1*64+t] + sAPart[2*64+t] + sAPart[3*64+t];
    sAlpha[t] = a * (float)sMaskArr[t];
  }
  __syncthreads();
  if (t < HH) {
    float acc = 0.0f;
    #pragma unroll
    for (int l = 0; l < 64; ++l) {
      int r = sAliasRow[l];
      acc = fmaf(sAlpha[l], b2f(sH[r * SH_STR + t]), acc);
    }
    sGlob[t] = acc;
  }
  __syncthreads();
  if (t < HH) {
    const float* w3r = w3 + t * 256;
    float a0 = b3[t], a1 = 0.0f;
    #pragma unroll
    for (int k = 0; k < HH; ++k) {
      a0 = fmaf(b2f(sH[lastRow * SH_STR + k]), w3r[k],      a0);
      a1 = fmaf(sGlob[k],                      w3r[HH + k], a1);
    }
    out[b * HH + t] = a0 + a1;
  }
}

extern "C" void kernel_launch(void* const* d_in, const int* in_sizes, int n_in,
                              void* d_out, int out_size, void* d_ws, size_t ws_size,
                              hipStream_t stream) {
  const float* A          = (const float*)d_in[0];
  const int*   items      = (const int*)  d_in[1];
  const int*   mask       = (const int*)  d_in[2];
  const int*   alias_in   = (const int*)  d_in[3];
  const float* emb        = (const float*)d_in[4];
  const float* w_in       = (const float*)d_in[5];
  const float* b_in       = (const float*)d_in[6];
  const float* w_out      = (const float*)d_in[7];
  const float* b_out      = (const float*)d_in[8];
  const float* b_iah      = (const float*)d_in[9];
  const float* b_oah      = (const float*)d_in[10];
  const float* wi         = (const float*)d_in[11];
  const float* bi         = (const float*)d_in[12];
  const float* wh         = (const float*)d_in[13];
  const float* bh         = (const float*)d_in[14];
  const float* w1         = (const float*)d_in[15];
  const float* b1         = (const float*)d_in[16];
  const float* w2         = (const float*)d_in[17];
  const float* b2         = (const float*)d_in[18];
  const float* wq         = (const float*)d_in[19];
  const float* w3         = (const float*)d_in[20];
  const float* b3         = (const float*)d_in[21];
  float* out = (float*)d_out;

  hipLaunchKernelGGL(srgnn_kernel, dim3(NB), dim3(BDIM), 0, stream,
                     A, items, mask, alias_in, emb,
                     w_in, b_in, w_out, b_out, b_iah, b_oah,
                     wi, bi, wh, bh, w1, b1, w2, b2, wq, w3, b3, out);
}

// Round 4
// 3024.207 us; speedup vs baseline: 9.6617x; 9.4907x over previous
//
#include <hip/hip_runtime.h>
#include <stdint.h>

// SR-GNN fused kernel. R4: ALL weights staged global(fp32)->LDS(bf16) in tiles
// with coalesced wide loads; inner loops read weights as LDS broadcasts.
// R3's counters showed ~40 GB FETCH = per-iteration uniform weight loads each
// fetching their own 64B line at ~900cyc, fully latency-serialized.

#define BDIM 256
#define NB   1024
#define NN   64
#define HH   128

#define SH_STR 132   // u16; row = 264B (8B aligned)
#define SX_STR 268   // u16; row = 536B (8B aligned)
#define WH_OFF 6144  // u16 offset of wh region inside sW

// bias LDS offsets (floats)
#define OFF_BIN  0
#define OFF_BOUT 128
#define OFF_BIAH 256
#define OFF_BOAH 384
#define OFF_BI   512
#define OFF_BH   896
#define OFF_B1   1280
#define OFF_B2   1408
#define OFF_WQ   1536
#define OFF_B3   1664

__device__ __forceinline__ float b2f_lo(uint32_t u){
  union { uint32_t u; float f; } v; v.u = u << 16; return v.f;
}
__device__ __forceinline__ float b2f_hi(uint32_t u){
  union { uint32_t u; float f; } v; v.u = u & 0xffff0000u; return v.f;
}
__device__ __forceinline__ uint16_t f2b(float f){
  union { float f; uint32_t u; } v; v.f = f;
  uint32_t r = v.u + 0x7fffu + ((v.u >> 16) & 1u);   // RNE
  return (uint16_t)(r >> 16);
}
__device__ __forceinline__ float b2f(uint16_t s){
  union { uint32_t u; float f; } v; v.u = ((uint32_t)s) << 16; return v.f;
}
__device__ __forceinline__ float sig_f(float x){
  return 1.0f / (1.0f + __expf(-x));
}
__device__ __forceinline__ float tanh_f(float x){
  return 1.0f - 2.0f / (__expf(2.0f * x) + 1.0f);
}

__global__ __launch_bounds__(BDIM, 2) void srgnn_kernel(
    const float* __restrict__ A,
    const int*   __restrict__ items,
    const int*   __restrict__ mask,
    const int*   __restrict__ alias_input,
    const float* __restrict__ emb,
    const float* __restrict__ w_in,  const float* __restrict__ b_in,
    const float* __restrict__ w_out, const float* __restrict__ b_out,
    const float* __restrict__ b_iah, const float* __restrict__ b_oah,
    const float* __restrict__ wi,    const float* __restrict__ bi,
    const float* __restrict__ wh,    const float* __restrict__ bh,
    const float* __restrict__ w1,    const float* __restrict__ b1,
    const float* __restrict__ w2,    const float* __restrict__ b2,
    const float* __restrict__ wq,
    const float* __restrict__ w3,    const float* __restrict__ b3,
    float* __restrict__ out)
{
  __shared__ __align__(16) uint16_t sH[NN * SH_STR];   // 16.9 KB hidden bf16
  __shared__ __align__(16) uint16_t sX[NN * SX_STR];   // 34.3 KB ie bf16 / P4 weights
  __shared__ __align__(16) uint16_t sW[9216];          // 18.4 KB weight tiles
  __shared__ float sB[1792];                           // 7.2 KB biases
  __shared__ float sQ1[HH];
  __shared__ float sGlob[HH];
  __shared__ float sAPart[4][64];
  __shared__ float sAlpha[64];
  __shared__ int   sAliasRow[64];
  __shared__ int   sMaskArr[64];

  const int t    = threadIdx.x;
  const int b    = blockIdx.x;
  const int lane = t & 63;
  const int wv   = __builtin_amdgcn_readfirstlane(t >> 6);

  // ---------- P0: embeddings + biases + alias/mask ----------
  {
    const int* itb = items + b * NN;
    for (int j = t; j < NN * HH; j += BDIM) {
      int n = j >> 7, k = j & 127;
      int it = itb[n];
      sH[n * SH_STR + k] = f2b(emb[(size_t)it * HH + k]);
    }
    if (t < 128) {
      sB[OFF_BIN  + t] = b_in[t];
      sB[OFF_BOUT + t] = b_out[t];
      sB[OFF_BIAH + t] = b_iah[t];
      sB[OFF_BOAH + t] = b_oah[t];
      sB[OFF_B1 + t] = b1[t];
      sB[OFF_B2 + t] = b2[t];
      sB[OFF_WQ + t] = wq[t];
      sB[OFF_B3 + t] = b3[t];
    }
    for (int j = t; j < 384; j += BDIM) {
      sB[OFF_BI + j] = bi[j];
      sB[OFF_BH + j] = bh[j];
    }
    if (t < 64) {
      sAliasRow[t] = alias_input[b * 64 + t];
      sMaskArr[t]  = mask[b * 64 + t];
    }
  }
  __syncthreads();

  uint32_t hreg[64];   // lane's hidden row (128 bf16) — loaded at step start

  for (int step = 0; step < 2; ++step) {
    // load own hidden row into regs
    {
      const uint2* hr2 = reinterpret_cast<const uint2*>(&sH[lane * SH_STR]);
      #pragma unroll
      for (int j = 0; j < 32; ++j) { uint2 v = hr2[j]; hreg[2*j] = v.x; hreg[2*j+1] = v.y; }
    }

    // ---------- P1: sX[n][c] = bias[c] + sum_k h[n][k] * w[c][k] ----------
    // 8 tiles of 32 cols; weights staged fp32->bf16 into sW (32x128)
    for (int T = 0; T < 8; ++T) {
      // stage
      for (int idx = t; idx < 32 * 128; idx += BDIM) {
        int r = idx >> 7, k = idx & 127;
        int c = T * 32 + r;
        const float* src = (c < 128) ? (w_in + c * 128) : (w_out + (c - 128) * 128);
        sW[r * 128 + k] = f2b(src[k]);
      }
      __syncthreads();
      // compute: wave wv does cols [wv*8, wv*8+8) of the tile
      #pragma unroll 1
      for (int i = 0; i < 8; ++i) {
        int cl = wv * 8 + i;
        int c  = T * 32 + cl;
        const uint4* wr4 = reinterpret_cast<const uint4*>(&sW[cl * 128]);
        float a0 = sB[c], a1 = 0.f, a2 = 0.f, a3 = 0.f;   // sB[0..255] = b_in||b_out
        #pragma unroll
        for (int j = 0; j < 16; ++j) {
          uint4 w = wr4[j];
          uint32_t h0 = hreg[4*j], h1 = hreg[4*j+1], h2 = hreg[4*j+2], h3 = hreg[4*j+3];
          a0 = fmaf(b2f_lo(h0), b2f_lo(w.x), a0); a1 = fmaf(b2f_hi(h0), b2f_hi(w.x), a1);
          a0 = fmaf(b2f_lo(h1), b2f_lo(w.y), a0); a1 = fmaf(b2f_hi(h1), b2f_hi(w.y), a1);
          a2 = fmaf(b2f_lo(h2), b2f_lo(w.z), a2); a3 = fmaf(b2f_hi(h2), b2f_hi(w.z), a3);
          a2 = fmaf(b2f_lo(h3), b2f_lo(w.w), a2); a3 = fmaf(b2f_hi(h3), b2f_hi(w.w), a3);
        }
        sX[lane * SX_STR + c] = f2b((a0 + a1) + (a2 + a3));
      }
      __syncthreads();
    }

    // ---------- P2: ie = A_in @ h_in | A_out @ h_out, in place over sX ----
    {
      const float* Ab = A + ((size_t)b * NN + lane) * (2 * NN);
      float areg[64];
      const float4* Ab4 = reinterpret_cast<const float4*>(Ab);
      #pragma unroll
      for (int m = 0; m < 16; ++m) {
        float4 v = Ab4[m];
        areg[4*m] = v.x; areg[4*m+1] = v.y; areg[4*m+2] = v.z; areg[4*m+3] = v.w;
      }
      #pragma unroll 1
      for (int i = 0; i < 16; ++i) {
        int cc = wv * 32 + 2 * i;
        float e0 = sB[OFF_BIAH + cc], e1 = 0.f, o0 = sB[OFF_BIAH + cc + 1], o1 = 0.f;
        #pragma unroll
        for (int m = 0; m < 64; m += 2) {
          uint32_t u0 = *reinterpret_cast<const uint32_t*>(&sX[(m+0) * SX_STR + cc]);
          uint32_t u1 = *reinterpret_cast<const uint32_t*>(&sX[(m+1) * SX_STR + cc]);
          e0 = fmaf(areg[m+0], b2f_lo(u0), e0);
          o0 = fmaf(areg[m+0], b2f_hi(u0), o0);
          e1 = fmaf(areg[m+1], b2f_lo(u1), e1);
          o1 = fmaf(areg[m+1], b2f_hi(u1), o1);
        }
        uint32_t w = (uint32_t)f2b(e0 + e1) | ((uint32_t)f2b(o0 + o1) << 16);
        *reinterpret_cast<uint32_t*>(&sX[lane * SX_STR + cc]) = w;
      }
      #pragma unroll
      for (int m = 0; m < 16; ++m) {
        float4 v = Ab4[16 + m];
        areg[4*m] = v.x; areg[4*m+1] = v.y; areg[4*m+2] = v.z; areg[4*m+3] = v.w;
      }
      #pragma unroll 1
      for (int i = 0; i < 16; ++i) {
        int cc = 128 + wv * 32 + 2 * i;
        float e0 = sB[OFF_BOAH + cc - 128], e1 = 0.f, o0 = sB[OFF_BOAH + cc - 127], o1 = 0.f;
        #pragma unroll
        for (int m = 0; m < 64; m += 2) {
          uint32_t u0 = *reinterpret_cast<const uint32_t*>(&sX[(m+0) * SX_STR + cc]);
          uint32_t u1 = *reinterpret_cast<const uint32_t*>(&sX[(m+1) * SX_STR + cc]);
          e0 = fmaf(areg[m+0], b2f_lo(u0), e0);
          o0 = fmaf(areg[m+0], b2f_hi(u0), o0);
          e1 = fmaf(areg[m+1], b2f_lo(u1), e1);
          o1 = fmaf(areg[m+1], b2f_hi(u1), o1);
        }
        uint32_t w = (uint32_t)f2b(e0 + e1) | ((uint32_t)f2b(o0 + o1) << 16);
        *reinterpret_cast<uint32_t*>(&sX[lane * SX_STR + cc]) = w;
      }
    }
    __syncthreads();

    // ---------- P3: gates; 16 tiles of 8 h; writes new hidden into sH ------
    for (int T = 0; T < 16; ++T) {
      // stage wi rows (24 x 256) and wh rows (24 x 128): r>>3 = gate, r&7 = local h
      for (int idx = t; idx < 24 * 256; idx += BDIM) {
        int r = idx >> 8, k = idx & 255;
        int g = (r >> 3) * 128 + T * 8 + (r & 7);
        sW[r * 256 + k] = f2b(wi[(size_t)g * 256 + k]);
      }
      for (int idx = t; idx < 24 * 128; idx += BDIM) {
        int r = idx >> 7, k = idx & 127;
        int g = (r >> 3) * 128 + T * 8 + (r & 7);
        sW[WH_OFF + r * 128 + k] = f2b(wh[(size_t)g * 128 + k]);
      }
      __syncthreads();

      const int lh0 = wv * 2;              // local h pair in tile
      const int h0g = T * 8 + lh0, h1g = h0g + 1;
      float ir0 = sB[OFF_BI + h0g],       ir1 = sB[OFF_BI + h1g];
      float ii0 = sB[OFF_BI + 128 + h0g], ii1 = sB[OFF_BI + 128 + h1g];
      float in0 = sB[OFF_BI + 256 + h0g], in1 = sB[OFF_BI + 256 + h1g];
      float hr0 = sB[OFF_BH + h0g],       hr1 = sB[OFF_BH + h1g];
      float hi0 = sB[OFF_BH + 128 + h0g], hi1 = sB[OFF_BH + 128 + h1g];
      float hn0 = sB[OFF_BH + 256 + h0g], hn1 = sB[OFF_BH + 256 + h1g];

      // ie part: own sX row (bf16 x256) against 6 wi-rows
      {
        const uint2* xr = reinterpret_cast<const uint2*>(&sX[lane * SX_STR]);
        const uint4* pR0 = reinterpret_cast<const uint4*>(&sW[(0*8 + lh0) * 256]);
        const uint4* pR1 = reinterpret_cast<const uint4*>(&sW[(0*8 + lh0 + 1) * 256]);
        const uint4* pI0 = reinterpret_cast<const uint4*>(&sW[(1*8 + lh0) * 256]);
        const uint4* pI1 = reinterpret_cast<const uint4*>(&sW[(1*8 + lh0 + 1) * 256]);
        const uint4* pN0 = reinterpret_cast<const uint4*>(&sW[(2*8 + lh0) * 256]);
        const uint4* pN1 = reinterpret_cast<const uint4*>(&sW[(2*8 + lh0 + 1) * 256]);
        #pragma unroll 4
        for (int j = 0; j < 32; ++j) {
          uint2 e0 = xr[2*j], e1 = xr[2*j+1];
          float f0 = b2f_lo(e0.x), f1 = b2f_hi(e0.x), f2 = b2f_lo(e0.y), f3 = b2f_hi(e0.y);
          float f4 = b2f_lo(e1.x), f5 = b2f_hi(e1.x), f6 = b2f_lo(e1.y), f7 = b2f_hi(e1.y);
          uint4 w;
          w = pR0[j];
          ir0 = fmaf(f0, b2f_lo(w.x), ir0); ir0 = fmaf(f1, b2f_hi(w.x), ir0);
          ir0 = fmaf(f2, b2f_lo(w.y), ir0); ir0 = fmaf(f3, b2f_hi(w.y), ir0);
          ir0 = fmaf(f4, b2f_lo(w.z), ir0); ir0 = fmaf(f5, b2f_hi(w.z), ir0);
          ir0 = fmaf(f6, b2f_lo(w.w), ir0); ir0 = fmaf(f7, b2f_hi(w.w), ir0);
          w = pR1[j];
          ir1 = fmaf(f0, b2f_lo(w.x), ir1); ir1 = fmaf(f1, b2f_hi(w.x), ir1);
          ir1 = fmaf(f2, b2f_lo(w.y), ir1); ir1 = fmaf(f3, b2f_hi(w.y), ir1);
          ir1 = fmaf(f4, b2f_lo(w.z), ir1); ir1 = fmaf(f5, b2f_hi(w.z), ir1);
          ir1 = fmaf(f6, b2f_lo(w.w), ir1); ir1 = fmaf(f7, b2f_hi(w.w), ir1);
          w = pI0[j];
          ii0 = fmaf(f0, b2f_lo(w.x), ii0); ii0 = fmaf(f1, b2f_hi(w.x), ii0);
          ii0 = fmaf(f2, b2f_lo(w.y), ii0); ii0 = fmaf(f3, b2f_hi(w.y), ii0);
          ii0 = fmaf(f4, b2f_lo(w.z), ii0); ii0 = fmaf(f5, b2f_hi(w.z), ii0);
          ii0 = fmaf(f6, b2f_lo(w.w), ii0); ii0 = fmaf(f7, b2f_hi(w.w), ii0);
          w = pI1[j];
          ii1 = fmaf(f0, b2f_lo(w.x), ii1); ii1 = fmaf(f1, b2f_hi(w.x), ii1);
          ii1 = fmaf(f2, b2f_lo(w.y), ii1); ii1 = fmaf(f3, b2f_hi(w.y), ii1);
          ii1 = fmaf(f4, b2f_lo(w.z), ii1); ii1 = fmaf(f5, b2f_hi(w.z), ii1);
          ii1 = fmaf(f6, b2f_lo(w.w), ii1); ii1 = fmaf(f7, b2f_hi(w.w), ii1);
          w = pN0[j];
          in0 = fmaf(f0, b2f_lo(w.x), in0); in0 = fmaf(f1, b2f_hi(w.x), in0);
          in0 = fmaf(f2, b2f_lo(w.y), in0); in0 = fmaf(f3, b2f_hi(w.y), in0);
          in0 = fmaf(f4, b2f_lo(w.z), in0); in0 = fmaf(f5, b2f_hi(w.z), in0);
          in0 = fmaf(f6, b2f_lo(w.w), in0); in0 = fmaf(f7, b2f_hi(w.w), in0);
          w = pN1[j];
          in1 = fmaf(f0, b2f_lo(w.x), in1); in1 = fmaf(f1, b2f_hi(w.x), in1);
          in1 = fmaf(f2, b2f_lo(w.y), in1); in1 = fmaf(f3, b2f_hi(w.y), in1);
          in1 = fmaf(f4, b2f_lo(w.z), in1); in1 = fmaf(f5, b2f_hi(w.z), in1);
          in1 = fmaf(f6, b2f_lo(w.w), in1); in1 = fmaf(f7, b2f_hi(w.w), in1);
        }
      }
      // gh part: hreg against 6 wh-rows
      {
        const uint4* qR0 = reinterpret_cast<const uint4*>(&sW[WH_OFF + (0*8 + lh0) * 128]);
        const uint4* qR1 = reinterpret_cast<const uint4*>(&sW[WH_OFF + (0*8 + lh0 + 1) * 128]);
        const uint4* qI0 = reinterpret_cast<const uint4*>(&sW[WH_OFF + (1*8 + lh0) * 128]);
        const uint4* qI1 = reinterpret_cast<const uint4*>(&sW[WH_OFF + (1*8 + lh0 + 1) * 128]);
        const uint4* qN0 = reinterpret_cast<const uint4*>(&sW[WH_OFF + (2*8 + lh0) * 128]);
        const uint4* qN1 = reinterpret_cast<const uint4*>(&sW[WH_OFF + (2*8 + lh0 + 1) * 128]);
        #pragma unroll 4
        for (int j = 0; j < 16; ++j) {
          uint32_t g0 = hreg[4*j], g1 = hreg[4*j+1], g2 = hreg[4*j+2], g3 = hreg[4*j+3];
          float f0 = b2f_lo(g0), f1 = b2f_hi(g0), f2 = b2f_lo(g1), f3 = b2f_hi(g1);
          float f4 = b2f_lo(g2), f5 = b2f_hi(g2), f6 = b2f_lo(g3), f7 = b2f_hi(g3);
          uint4 w;
          w = qR0[j];
          hr0 = fmaf(f0, b2f_lo(w.x), hr0); hr0 = fmaf(f1, b2f_hi(w.x), hr0);
          hr0 = fmaf(f2, b2f_lo(w.y), hr0); hr0 = fmaf(f3, b2f_hi(w.y), hr0);
          hr0 = fmaf(f4, b2f_lo(w.z), hr0); hr0 = fmaf(f5, b2f_hi(w.z), hr0);
          hr0 = fmaf(f6, b2f_lo(w.w), hr0); hr0 = fmaf(f7, b2f_hi(w.w), hr0);
          w = qR1[j];
          hr1 = fmaf(f0, b2f_lo(w.x), hr1); hr1 = fmaf(f1, b2f_hi(w.x), hr1);
          hr1 = fmaf(f2, b2f_lo(w.y), hr1); hr1 = fmaf(f3, b2f_hi(w.y), hr1);
          hr1 = fmaf(f4, b2f_lo(w.z), hr1); hr1 = fmaf(f5, b2f_hi(w.z), hr1);
          hr1 = fmaf(f6, b2f_lo(w.w), hr1); hr1 = fmaf(f7, b2f_hi(w.w), hr1);
          w = qI0[j];
          hi0 = fmaf(f0, b2f_lo(w.x), hi0); hi0 = fmaf(f1, b2f_hi(w.x), hi0);
          hi0 = fmaf(f2, b2f_lo(w.y), hi0); hi0 = fmaf(f3, b2f_hi(w.y), hi0);
          hi0 = fmaf(f4, b2f_lo(w.z), hi0); hi0 = fmaf(f5, b2f_hi(w.z), hi0);
          hi0 = fmaf(f6, b2f_lo(w.w), hi0); hi0 = fmaf(f7, b2f_hi(w.w), hi0);
          w = qI1[j];
          hi1 = fmaf(f0, b2f_lo(w.x), hi1); hi1 = fmaf(f1, b2f_hi(w.x), hi1);
          hi1 = fmaf(f2, b2f_lo(w.y), hi1); hi1 = fmaf(f3, b2f_hi(w.y), hi1);
          hi1 = fmaf(f4, b2f_lo(w.z), hi1); hi1 = fmaf(f5, b2f_hi(w.z), hi1);
          hi1 = fmaf(f6, b2f_lo(w.w), hi1); hi1 = fmaf(f7, b2f_hi(w.w), hi1);
          w = qN0[j];
          hn0 = fmaf(f0, b2f_lo(w.x), hn0); hn0 = fmaf(f1, b2f_hi(w.x), hn0);
          hn0 = fmaf(f2, b2f_lo(w.y), hn0); hn0 = fmaf(f3, b2f_hi(w.y), hn0);
          hn0 = fmaf(f4, b2f_lo(w.z), hn0); hn0 = fmaf(f5, b2f_hi(w.z), hn0);
          hn0 = fmaf(f6, b2f_lo(w.w), hn0); hn0 = fmaf(f7, b2f_hi(w.w), hn0);
          w = qN1[j];
          hn1 = fmaf(f0, b2f_lo(w.x), hn1); hn1 = fmaf(f1, b2f_hi(w.x), hn1);
          hn1 = fmaf(f2, b2f_lo(w.y), hn1); hn1 = fmaf(f3, b2f_hi(w.y), hn1);
          hn1 = fmaf(f4, b2f_lo(w.z), hn1); hn1 = fmaf(f5, b2f_hi(w.z), hn1);
          hn1 = fmaf(f6, b2f_lo(w.w), hn1); hn1 = fmaf(f7, b2f_hi(w.w), hn1);
        }
      }
      // gates + in-place hidden update (gh from hreg, so sH overwrite is safe)
      {
        float z0 = sig_f(ii0 + hi0), z1 = sig_f(ii1 + hi1);
        float r0 = sig_f(ir0 + hr0), r1 = sig_f(ir1 + hr1);
        float g0 = tanh_f(fmaf(r0, hn0, in0)), g1 = tanh_f(fmaf(r1, hn1, in1));
        uint32_t hp = hreg[h0g >> 1];
        float hp0 = b2f_lo(hp), hp1 = b2f_hi(hp);
        float nh0 = fmaf(z0, g0 - hp0, hp0);
        float nh1 = fmaf(z1, g1 - hp1, hp1);
        uint32_t pk = (uint32_t)f2b(nh0) | ((uint32_t)f2b(nh1) << 16);
        *reinterpret_cast<uint32_t*>(&sH[lane * SH_STR + h0g]) = pk;
      }
      __syncthreads();
    }
  }

  // ---------- P4: attention readout (weights staged into dead sX) ----------
  int msum = 0;
  #pragma unroll
  for (int l = 0; l < 64; ++l) msum += sMaskArr[l];
  const int lastRow = sAliasRow[msum - 1];
  uint16_t* sP4 = sX;

  // q1 = local @ w1.T + b1 ; stage w1 (128x128, stride 132)
  for (int idx = t; idx < 128 * 128; idx += BDIM) {
    int r = idx >> 7, k = idx & 127;
    sP4[r * 132 + k] = f2b(w1[idx]);
  }
  __syncthreads();
  if (t < HH) {
    const uint2* w1r = reinterpret_cast<const uint2*>(&sP4[t * 132]);
    const uint2* lr  = reinterpret_cast<const uint2*>(&sH[lastRow * SH_STR]);
    float a0 = sB[OFF_B1 + t], a1 = 0.f, a2 = 0.f, a3 = 0.f;
    #pragma unroll 8
    for (int j = 0; j < 32; ++j) {
      uint2 w = w1r[j]; uint2 v = lr[j];
      a0 = fmaf(b2f_lo(v.x), b2f_lo(w.x), a0); a1 = fmaf(b2f_hi(v.x), b2f_hi(w.x), a1);
      a2 = fmaf(b2f_lo(v.y), b2f_lo(w.y), a2); a3 = fmaf(b2f_hi(v.y), b2f_hi(w.y), a3);
    }
    sQ1[t] = (a0 + a1) + (a2 + a3);
  }
  __syncthreads();

  // stage w2 (128x128, stride 132)
  for (int idx = t; idx < 128 * 128; idx += BDIM) {
    int r = idx >> 7, k = idx & 127;
    sP4[r * 132 + k] = f2b(w2[idx]);
  }
  __syncthreads();
  // alpha partials: lane = l, wave wv covers h in [wv*32, wv*32+32)
  {
    uint32_t sreg[64];
    const int myrow = sAliasRow[lane];
    const uint2* sr2 = reinterpret_cast<const uint2*>(&sH[myrow * SH_STR]);
    #pragma unroll
    for (int j = 0; j < 32; ++j) { uint2 v = sr2[j]; sreg[2*j] = v.x; sreg[2*j+1] = v.y; }
    float apart = 0.0f;
    #pragma unroll 1
    for (int i = 0; i < 32; ++i) {
      int h = wv * 32 + i;
      const uint2* w2r = reinterpret_cast<const uint2*>(&sP4[h * 132]);
      float a0 = sB[OFF_B2 + h], a1 = 0.f, a2 = 0.f, a3 = 0.f;
      #pragma unroll 8
      for (int j = 0; j < 32; ++j) {
        uint2 w = w2r[j];
        uint32_t v0 = sreg[2*j], v1 = sreg[2*j+1];
        a0 = fmaf(b2f_lo(v0), b2f_lo(w.x), a0); a1 = fmaf(b2f_hi(v0), b2f_hi(w.x), a1);
        a2 = fmaf(b2f_lo(v1), b2f_lo(w.y), a2); a3 = fmaf(b2f_hi(v1), b2f_hi(w.y), a3);
      }
      apart += sig_f(sQ1[h] + (a0 + a1) + (a2 + a3)) * sB[OFF_WQ + h];
    }
    sAPart[wv][lane] = apart;
  }
  __syncthreads();
  if (t < 64) {
    float a = sAPart[0][t] + sAPart[1][t] + sAPart[2][t] + sAPart[3][t];
    sAlpha[t] = a * (float)sMaskArr[t];
  }
  __syncthreads();
  if (t < HH) {
    float acc = 0.0f;
    #pragma unroll
    for (int l = 0; l < 64; ++l) {
      int r = sAliasRow[l];
      acc = fmaf(sAlpha[l], b2f(sH[r * SH_STR + t]), acc);
    }
    sGlob[t] = acc;
  }
  __syncthreads();

  // out = [local|glob] @ w3.T + b3 ; 2 tiles of 64 rows (stride 264)
  for (int T3 = 0; T3 < 2; ++T3) {
    for (int idx = t; idx < 64 * 256; idx += BDIM) {
      int r = idx >> 8, k = idx & 255;
      sP4[r * 264 + k] = f2b(w3[(size_t)(T3 * 64 + r) * 256 + k]);
    }
    __syncthreads();
    {
      int o = t & 63, q = t >> 6;
      const uint2* w3r = reinterpret_cast<const uint2*>(&sP4[o * 264 + q * 64]);
      float a0 = 0.f, a1 = 0.f, a2 = 0.f, a3 = 0.f;
      if (q < 2) {
        const uint2* lr = reinterpret_cast<const uint2*>(&sH[lastRow * SH_STR + q * 64]);
        #pragma unroll 8
        for (int j = 0; j < 16; ++j) {
          uint2 w = w3r[j]; uint2 v = lr[j];
          a0 = fmaf(b2f_lo(v.x), b2f_lo(w.x), a0); a1 = fmaf(b2f_hi(v.x), b2f_hi(w.x), a1);
          a2 = fmaf(b2f_lo(v.y), b2f_lo(w.y), a2); a3 = fmaf(b2f_hi(v.y), b2f_hi(w.y), a3);
        }
      } else {
        const float* gp = sGlob + (q - 2) * 64;
        #pragma unroll 8
        for (int j = 0; j < 16; ++j) {
          uint2 w = w3r[j];
          a0 = fmaf(gp[4*j+0], b2f_lo(w.x), a0); a1 = fmaf(gp[4*j+1], b2f_hi(w.x), a1);
          a2 = fmaf(gp[4*j+2], b2f_lo(w.y), a2); a3 = fmaf(gp[4*j+3], b2f_hi(w.y), a3);
        }
      }
      sAPart[q][o] = (a0 + a1) + (a2 + a3);
    }
    __syncthreads();
    if (t < 64) {
      float r = sB[OFF_B3 + T3 * 64 + t]
              + sAPart[0][t] + sAPart[1][t] + sAPart[2][t] + sAPart[3][t];
      out[b * HH + T3 * 64 + t] = r;
    }
    __syncthreads();
  }
}

extern "C" void kernel_launch(void* const* d_in, const int* in_sizes, int n_in,
                              void* d_out, int out_size, void* d_ws, size_t ws_size,
                              hipStream_t stream) {
  const float* A          = (const float*)d_in[0];
  const int*   items      = (const int*)  d_in[1];
  const int*   mask       = (const int*)  d_in[2];
  const int*   alias_in   = (const int*)  d_in[3];
  const float* emb        = (const float*)d_in[4];
  const float* w_in       = (const float*)d_in[5];
  const float* b_in       = (const float*)d_in[6];
  const float* w_out      = (const float*)d_in[7];
  const float* b_out      = (const float*)d_in[8];
  const float* b_iah      = (const float*)d_in[9];
  const float* b_oah      = (const float*)d_in[10];
  const float* wi         = (const float*)d_in[11];
  const float* bi         = (const float*)d_in[12];
  const float* wh         = (const float*)d_in[13];
  const float* bh         = (const float*)d_in[14];
  const float* w1         = (const float*)d_in[15];
  const float* b1         = (const float*)d_in[16];
  const float* w2         = (const float*)d_in[17];
  const float* b2         = (const float*)d_in[18];
  const float* wq         = (const float*)d_in[19];
  const float* w3         = (const float*)d_in[20];
  const float* b3         = (const float*)d_in[21];
  float* out = (float*)d_out;

  hipLaunchKernelGGL(srgnn_kernel, dim3(NB), dim3(BDIM), 0, stream,
                     A, items, mask, alias_in, emb,
                     w_in, b_in, w_out, b_out, b_iah, b_oah,
                     wi, bi, wh, bh, w1, b1, w2, b2, wq, w3, b3, out);
}

// Round 5
// 553.539 us; speedup vs baseline: 52.7858x; 5.4634x over previous
//
#include <hip/hip_runtime.h>
#include <stdint.h>

// SR-GNN fused kernel, R5: MFMA (v_mfma_f32_16x16x32_bf16) for all GEMM phases.
// One wg per batch element. Hidden + ie live in LDS bf16; weights stream
// global->reg with in-reg fp32->bf16 pack; waves own disjoint 16-col blocks so
// in-place LDS updates are race-free. P4 readout kept as R4's VALU code.

#define BDIM 256
#define NB   1024
#define NN   64
#define HH   128
#define SH_STR 136   // u16 stride; 272B rows, (r+q) bank-balanced for b128
#define SX_STR 264   // u16 stride; 528B rows, (r+q) bank-balanced for b128

typedef short v8s __attribute__((ext_vector_type(8)));
typedef float v4f __attribute__((ext_vector_type(4)));

__device__ __forceinline__ float b2f_lo(uint32_t u){
  union { uint32_t u; float f; } v; v.u = u << 16; return v.f;
}
__device__ __forceinline__ float b2f_hi(uint32_t u){
  union { uint32_t u; float f; } v; v.u = u & 0xffff0000u; return v.f;
}
__device__ __forceinline__ uint16_t f2b(float f){   // RNE, for activations
  union { float f; uint32_t u; } v; v.f = f;
  uint32_t r = v.u + 0x7fffu + ((v.u >> 16) & 1u);
  return (uint16_t)(r >> 16);
}
__device__ __forceinline__ float b2f(uint16_t s){
  union { uint32_t u; float f; } v; v.u = ((uint32_t)s) << 16; return v.f;
}
__device__ __forceinline__ float sig_f(float x){ return 1.0f / (1.0f + __expf(-x)); }
__device__ __forceinline__ float tanh_f(float x){ return 1.0f - 2.0f / (__expf(2.0f*x) + 1.0f); }

// round-half-up f32->bf16 for two floats, packed into one dword (a=lo16, b=hi16)
__device__ __forceinline__ uint32_t pack2bf(float a, float b){
  union { float f; uint32_t u; } ua, ub; ua.f = a; ub.f = b;
  return __builtin_amdgcn_perm(ub.u + 0x8000u, ua.u + 0x8000u, 0x07060302u);
}

// B-frag (or A-frag) from row-major fp32 global: elem j = W[row_base+r][k_base+q*8+j]
__device__ __forceinline__ v8s ldwB(const float* __restrict__ W, int ld,
                                    int row_base, int k_base, int r, int q){
  const float* p = W + (size_t)(row_base + r) * ld + k_base + q * 8;
  float4 f0 = *reinterpret_cast<const float4*>(p);
  float4 f1 = *reinterpret_cast<const float4*>(p + 4);
  union { uint32_t u[4]; v8s v; } o;
  o.u[0] = pack2bf(f0.x, f0.y);
  o.u[1] = pack2bf(f0.z, f0.w);
  o.u[2] = pack2bf(f1.x, f1.y);
  o.u[3] = pack2bf(f1.z, f1.w);
  return o.v;
}

// A-frag from LDS bf16 row-major: elem j = buf[row_base+r][k_base+q*8+j]
__device__ __forceinline__ v8s ldsA(const uint16_t* buf, int stride,
                                    int row_base, int k_base, int r, int q){
  return *reinterpret_cast<const v8s*>(&buf[(row_base + r) * stride + k_base + q * 8]);
}

#define MFMA(a, b, c) __builtin_amdgcn_mfma_f32_16x16x32_bf16((a), (b), (c), 0, 0, 0)

__global__ __launch_bounds__(BDIM, 2) void srgnn_kernel(
    const float* __restrict__ A,
    const int*   __restrict__ items,
    const int*   __restrict__ mask,
    const int*   __restrict__ alias_input,
    const float* __restrict__ emb,
    const float* __restrict__ w_in,  const float* __restrict__ b_in,
    const float* __restrict__ w_out, const float* __restrict__ b_out,
    const float* __restrict__ b_iah, const float* __restrict__ b_oah,
    const float* __restrict__ wi,    const float* __restrict__ bi,
    const float* __restrict__ wh,    const float* __restrict__ bh,
    const float* __restrict__ w1,    const float* __restrict__ b1,
    const float* __restrict__ w2,    const float* __restrict__ b2,
    const float* __restrict__ wq,
    const float* __restrict__ w3,    const float* __restrict__ b3,
    float* __restrict__ out)
{
  __shared__ __align__(16) uint16_t sH[NN * SH_STR];   // hidden bf16
  __shared__ __align__(16) uint16_t sX[NN * SX_STR];   // h_in|h_out -> ie bf16; P4 wt
  __shared__ float sBP[256];    // b_in || b_out
  __shared__ float sBA[256];    // b_iah || b_oah
  __shared__ float sBR[128];    // bi[r]+bh[r]
  __shared__ float sBI[128];    // bi[i]+bh[i]
  __shared__ float sBNi[128];   // bi[n]
  __shared__ float sBNh[128];   // bh[n]
  __shared__ float sB4[512];    // b1 | b2 | wq | b3
  __shared__ float sQ1[128], sGlob[128], sAPart[4][64], sAlpha[64];
  __shared__ int   sAliasRow[64], sMaskArr[64];

  const int t    = threadIdx.x;
  const int b    = blockIdx.x;
  const int lane = t & 63;
  const int wv   = __builtin_amdgcn_readfirstlane(t >> 6);
  const int r    = lane & 15;        // MFMA row/col select
  const int q    = lane >> 4;        // MFMA quad

  // ---------- P0: embeddings + biases + alias/mask ----------
  {
    const int* itb = items + b * NN;
    for (int j = t; j < NN * HH; j += BDIM) {
      int n = j >> 7, k = j & 127;
      sH[n * SH_STR + k] = f2b(emb[(size_t)itb[n] * HH + k]);
    }
    if (t < 128) {
      sBP[t] = b_in[t];  sBP[128 + t] = b_out[t];
      sBA[t] = b_iah[t]; sBA[128 + t] = b_oah[t];
      sBR[t]  = bi[t] + bh[t];
      sBI[t]  = bi[128 + t] + bh[128 + t];
      sBNi[t] = bi[256 + t];
      sBNh[t] = bh[256 + t];
      sB4[t] = b1[t]; sB4[128 + t] = b2[t]; sB4[256 + t] = wq[t]; sB4[384 + t] = b3[t];
    }
    if (t < 64) {
      sAliasRow[t] = alias_input[b * 64 + t];
      sMaskArr[t]  = mask[b * 64 + t];
    }
  }
  __syncthreads();

  for (int step = 0; step < 2; ++step) {
    // ---------- P1 (MFMA): sX[n][c] = bias[c] + sum_k H[n][k]*W[c][k] ----------
    {
      v8s a[4][4];                       // [mt][kk] from sH
      #pragma unroll
      for (int mt = 0; mt < 4; ++mt)
        #pragma unroll
        for (int kk = 0; kk < 4; ++kk)
          a[mt][kk] = ldsA(sH, SH_STR, mt * 16, kk * 32, r, q);

      const float* Wsel = (wv < 2) ? w_in : w_out;
      const int    wofs = (wv < 2) ? 0 : 128;
      #pragma unroll 1
      for (int i = 0; i < 4; ++i) {
        int nt = wv * 4 + i;
        int c  = nt * 16 + r;            // output column this lane owns
        float bini = sBP[c];
        v4f acc0 = {bini, bini, bini, bini}, acc1 = acc0, acc2 = acc0, acc3 = acc0;
        #pragma unroll
        for (int kk = 0; kk < 4; ++kk) {
          v8s bf = ldwB(Wsel, 128, nt * 16 - wofs, kk * 32, r, q);
          acc0 = MFMA(a[0][kk], bf, acc0);
          acc1 = MFMA(a[1][kk], bf, acc1);
          acc2 = MFMA(a[2][kk], bf, acc2);
          acc3 = MFMA(a[3][kk], bf, acc3);
        }
        #pragma unroll
        for (int reg = 0; reg < 4; ++reg) {
          sX[(0  + q * 4 + reg) * SX_STR + c] = f2b(acc0[reg]);
          sX[(16 + q * 4 + reg) * SX_STR + c] = f2b(acc1[reg]);
          sX[(32 + q * 4 + reg) * SX_STR + c] = f2b(acc2[reg]);
          sX[(48 + q * 4 + reg) * SX_STR + c] = f2b(acc3[reg]);
        }
      }
    }
    // no barrier: each wave reads back only its own columns in P2

    // ---------- P2 (MFMA): ie[n][c] = biah/boah[c] + sum_m Adj[n][m]*X[m][c] ----
    {
      const int half = wv >> 1;          // waves 0,1: A[:, :64]; waves 2,3: A[:, 64:]
      v8s a2[4][2];
      #pragma unroll
      for (int mt = 0; mt < 4; ++mt)
        #pragma unroll
        for (int kk = 0; kk < 2; ++kk) {
          const float* p = A + (size_t)(b * NN + mt * 16 + r) * (2 * NN)
                             + half * 64 + kk * 32 + q * 8;
          float4 f0 = *reinterpret_cast<const float4*>(p);
          float4 f1 = *reinterpret_cast<const float4*>(p + 4);
          union { uint32_t u[4]; v8s v; } o;
          o.u[0] = pack2bf(f0.x, f0.y); o.u[1] = pack2bf(f0.z, f0.w);
          o.u[2] = pack2bf(f1.x, f1.y); o.u[3] = pack2bf(f1.z, f1.w);
          a2[mt][kk] = o.v;
        }
      #pragma unroll 1
      for (int i = 0; i < 4; ++i) {
        int nt = wv * 4 + i;
        int c  = nt * 16 + r;
        v8s b0, b1f;                     // B[k=m][n=c] from sX, strided u16 reads
        #pragma unroll
        for (int j = 0; j < 8; ++j) {
          b0[j]  = (short)sX[(q * 8 + j) * SX_STR + c];
          b1f[j] = (short)sX[(32 + q * 8 + j) * SX_STR + c];
        }
        float bini = sBA[c];
        v4f acc0 = {bini, bini, bini, bini}, acc1 = acc0, acc2 = acc0, acc3 = acc0;
        acc0 = MFMA(a2[0][0], b0, acc0); acc0 = MFMA(a2[0][1], b1f, acc0);
        acc1 = MFMA(a2[1][0], b0, acc1); acc1 = MFMA(a2[1][1], b1f, acc1);
        acc2 = MFMA(a2[2][0], b0, acc2); acc2 = MFMA(a2[2][1], b1f, acc2);
        acc3 = MFMA(a2[3][0], b0, acc3); acc3 = MFMA(a2[3][1], b1f, acc3);
        #pragma unroll
        for (int reg = 0; reg < 4; ++reg) {
          sX[(0  + q * 4 + reg) * SX_STR + c] = f2b(acc0[reg]);
          sX[(16 + q * 4 + reg) * SX_STR + c] = f2b(acc1[reg]);
          sX[(32 + q * 4 + reg) * SX_STR + c] = f2b(acc2[reg]);
          sX[(48 + q * 4 + reg) * SX_STR + c] = f2b(acc3[reg]);
        }
      }
    }
    __syncthreads();   // P3 reads all columns of sX / rows of sH

    // ---------- P3 (MFMA): gates over h-cols [wv*32, wv*32+32) ----------
    {
      const int h0 = wv * 32;
      v4f aR[2][4], aI[2][4], aNi[2][4], aNh[2][4];
      #pragma unroll
      for (int u = 0; u < 2; ++u) {
        int h = h0 + u * 16 + r;
        float vR = sBR[h], vI = sBI[h], vNi = sBNi[h], vNh = sBNh[h];
        #pragma unroll
        for (int mt = 0; mt < 4; ++mt) {
          aR[u][mt]  = (v4f){vR, vR, vR, vR};
          aI[u][mt]  = (v4f){vI, vI, vI, vI};
          aNi[u][mt] = (v4f){vNi, vNi, vNi, vNi};
          aNh[u][mt] = (v4f){vNh, vNh, vNh, vNh};
        }
      }
      // gi: IE[64x256] @ wi^T
      #pragma unroll 1
      for (int kk = 0; kk < 8; ++kk) {
        v8s af0 = ldsA(sX, SX_STR, 0,  kk * 32, r, q);
        v8s af1 = ldsA(sX, SX_STR, 16, kk * 32, r, q);
        v8s af2 = ldsA(sX, SX_STR, 32, kk * 32, r, q);
        v8s af3 = ldsA(sX, SX_STR, 48, kk * 32, r, q);
        #pragma unroll
        for (int u = 0; u < 2; ++u) {
          int wr = h0 + u * 16;
          v8s bR = ldwB(wi, 256, wr,        kk * 32, r, q);
          v8s bI = ldwB(wi, 256, 128 + wr,  kk * 32, r, q);
          v8s bN = ldwB(wi, 256, 256 + wr,  kk * 32, r, q);
          aR[u][0]  = MFMA(af0, bR, aR[u][0]);  aR[u][1]  = MFMA(af1, bR, aR[u][1]);
          aR[u][2]  = MFMA(af2, bR, aR[u][2]);  aR[u][3]  = MFMA(af3, bR, aR[u][3]);
          aI[u][0]  = MFMA(af0, bI, aI[u][0]);  aI[u][1]  = MFMA(af1, bI, aI[u][1]);
          aI[u][2]  = MFMA(af2, bI, aI[u][2]);  aI[u][3]  = MFMA(af3, bI, aI[u][3]);
          aNi[u][0] = MFMA(af0, bN, aNi[u][0]); aNi[u][1] = MFMA(af1, bN, aNi[u][1]);
          aNi[u][2] = MFMA(af2, bN, aNi[u][2]); aNi[u][3] = MFMA(af3, bN, aNi[u][3]);
        }
      }
      // gh: H[64x128] @ wh^T
      #pragma unroll 1
      for (int kk = 0; kk < 4; ++kk) {
        v8s af0 = ldsA(sH, SH_STR, 0,  kk * 32, r, q);
        v8s af1 = ldsA(sH, SH_STR, 16, kk * 32, r, q);
        v8s af2 = ldsA(sH, SH_STR, 32, kk * 32, r, q);
        v8s af3 = ldsA(sH, SH_STR, 48, kk * 32, r, q);
        #pragma unroll
        for (int u = 0; u < 2; ++u) {
          int wr = h0 + u * 16;
          v8s bR = ldwB(wh, 128, wr,        kk * 32, r, q);
          v8s bI = ldwB(wh, 128, 128 + wr,  kk * 32, r, q);
          v8s bN = ldwB(wh, 128, 256 + wr,  kk * 32, r, q);
          aR[u][0]  = MFMA(af0, bR, aR[u][0]);  aR[u][1]  = MFMA(af1, bR, aR[u][1]);
          aR[u][2]  = MFMA(af2, bR, aR[u][2]);  aR[u][3]  = MFMA(af3, bR, aR[u][3]);
          aI[u][0]  = MFMA(af0, bI, aI[u][0]);  aI[u][1]  = MFMA(af1, bI, aI[u][1]);
          aI[u][2]  = MFMA(af2, bI, aI[u][2]);  aI[u][3]  = MFMA(af3, bI, aI[u][3]);
          aNh[u][0] = MFMA(af0, bN, aNh[u][0]); aNh[u][1] = MFMA(af1, bN, aNh[u][1]);
          aNh[u][2] = MFMA(af2, bN, aNh[u][2]); aNh[u][3] = MFMA(af3, bN, aNh[u][3]);
        }
      }
      __syncthreads();   // all sX/sH fragment reads done before sH overwrite

      // epilogue: z,r,g + in-place hidden update (own cols only)
      #pragma unroll
      for (int u = 0; u < 2; ++u) {
        int h = h0 + u * 16 + r;
        #pragma unroll
        for (int mt = 0; mt < 4; ++mt) {
          #pragma unroll
          for (int reg = 0; reg < 4; ++reg) {
            int row = mt * 16 + q * 4 + reg;
            float z  = sig_f(aI[u][mt][reg]);
            float rr = sig_f(aR[u][mt][reg]);
            float gg = tanh_f(fmaf(rr, aNh[u][mt][reg], aNi[u][mt][reg]));
            float hp = b2f(sH[row * SH_STR + h]);
            sH[row * SH_STR + h] = f2b(fmaf(z, gg - hp, hp));
          }
        }
      }
    }
    __syncthreads();
  }

  // ---------- P4: attention readout (VALU; weights staged into dead sX) ------
  int msum = 0;
  #pragma unroll
  for (int l = 0; l < 64; ++l) msum += sMaskArr[l];
  const int lastRow = sAliasRow[msum - 1];
  uint16_t* sP4 = sX;

  for (int idx = t; idx < 128 * 128; idx += BDIM) {
    int rr = idx >> 7, k = idx & 127;
    sP4[rr * 132 + k] = f2b(w1[idx]);
  }
  __syncthreads();
  if (t < HH) {
    const uint2* w1r = reinterpret_cast<const uint2*>(&sP4[t * 132]);
    const uint2* lr  = reinterpret_cast<const uint2*>(&sH[lastRow * SH_STR]);
    float a0 = sB4[t], a1 = 0.f, a2 = 0.f, a3 = 0.f;
    #pragma unroll 8
    for (int j = 0; j < 32; ++j) {
      uint2 w = w1r[j]; uint2 v = lr[j];
      a0 = fmaf(b2f_lo(v.x), b2f_lo(w.x), a0); a1 = fmaf(b2f_hi(v.x), b2f_hi(w.x), a1);
      a2 = fmaf(b2f_lo(v.y), b2f_lo(w.y), a2); a3 = fmaf(b2f_hi(v.y), b2f_hi(w.y), a3);
    }
    sQ1[t] = (a0 + a1) + (a2 + a3);
  }
  __syncthreads();

  for (int idx = t; idx < 128 * 128; idx += BDIM) {
    int rr = idx >> 7, k = idx & 127;
    sP4[rr * 132 + k] = f2b(w2[idx]);
  }
  __syncthreads();
  {
    uint32_t sreg[64];
    const int myrow = sAliasRow[lane];
    const uint2* sr2 = reinterpret_cast<const uint2*>(&sH[myrow * SH_STR]);
    #pragma unroll
    for (int j = 0; j < 32; ++j) { uint2 v = sr2[j]; sreg[2*j] = v.x; sreg[2*j+1] = v.y; }
    float apart = 0.0f;
    #pragma unroll 1
    for (int i = 0; i < 32; ++i) {
      int h = wv * 32 + i;
      const uint2* w2r = reinterpret_cast<const uint2*>(&sP4[h * 132]);
      float a0 = sB4[128 + h], a1 = 0.f, a2 = 0.f, a3 = 0.f;
      #pragma unroll 8
      for (int j = 0; j < 32; ++j) {
        uint2 w = w2r[j];
        uint32_t v0 = sreg[2*j], v1 = sreg[2*j+1];
        a0 = fmaf(b2f_lo(v0), b2f_lo(w.x), a0); a1 = fmaf(b2f_hi(v0), b2f_hi(w.x), a1);
        a2 = fmaf(b2f_lo(v1), b2f_lo(w.y), a2); a3 = fmaf(b2f_hi(v1), b2f_hi(w.y), a3);
      }
      apart += sig_f(sQ1[h] + (a0 + a1) + (a2 + a3)) * sB4[256 + h];
    }
    sAPart[wv][lane] = apart;
  }
  __syncthreads();
  if (t < 64) {
    float a = sAPart[0][t] + sAPart[1][t] + sAPart[2][t] + sAPart[3][t];
    sAlpha[t] = a * (float)sMaskArr[t];
  }
  __syncthreads();
  if (t < HH) {
    float acc = 0.0f;
    #pragma unroll
    for (int l = 0; l < 64; ++l) {
      int rr = sAliasRow[l];
      acc = fmaf(sAlpha[l], b2f(sH[rr * SH_STR + t]), acc);
    }
    sGlob[t] = acc;
  }
  __syncthreads();

  for (int T3 = 0; T3 < 2; ++T3) {
    for (int idx = t; idx < 64 * 256; idx += BDIM) {
      int rr = idx >> 8, k = idx & 255;
      sP4[rr * 264 + k] = f2b(w3[(size_t)(T3 * 64 + rr) * 256 + k]);
    }
    __syncthreads();
    {
      int o = t & 63, qq = t >> 6;
      const uint2* w3r = reinterpret_cast<const uint2*>(&sP4[o * 264 + qq * 64]);
      float a0 = 0.f, a1 = 0.f, a2 = 0.f, a3 = 0.f;
      if (qq < 2) {
        const uint2* lr = reinterpret_cast<const uint2*>(&sH[lastRow * SH_STR + qq * 64]);
        #pragma unroll 8
        for (int j = 0; j < 16; ++j) {
          uint2 w = w3r[j]; uint2 v = lr[j];
          a0 = fmaf(b2f_lo(v.x), b2f_lo(w.x), a0); a1 = fmaf(b2f_hi(v.x), b2f_hi(w.x), a1);
          a2 = fmaf(b2f_lo(v.y), b2f_lo(w.y), a2); a3 = fmaf(b2f_hi(v.y), b2f_hi(w.y), a3);
        }
      } else {
        const float* gp = sGlob + (qq - 2) * 64;
        #pragma unroll 8
        for (int j = 0; j < 16; ++j) {
          uint2 w = w3r[j];
          a0 = fmaf(gp[4*j+0], b2f_lo(w.x), a0); a1 = fmaf(gp[4*j+1], b2f_hi(w.x), a1);
          a2 = fmaf(gp[4*j+2], b2f_lo(w.y), a2); a3 = fmaf(gp[4*j+3], b2f_hi(w.y), a3);
        }
      }
      sAPart[qq][o] = (a0 + a1) + (a2 + a3);
    }
    __syncthreads();
    if (t < 64) {
      float rr = sB4[384 + T3 * 64 + t]
               + sAPart[0][t] + sAPart[1][t] + sAPart[2][t] + sAPart[3][t];
      out[b * HH + T3 * 64 + t] = rr;
    }
    __syncthreads();
  }
}

extern "C" void kernel_launch(void* const* d_in, const int* in_sizes, int n_in,
                              void* d_out, int out_size, void* d_ws, size_t ws_size,
                              hipStream_t stream) {
  const float* A          = (const float*)d_in[0];
  const int*   items      = (const int*)  d_in[1];
  const int*   mask       = (const int*)  d_in[2];
  const int*   alias_in   = (const int*)  d_in[3];
  const float* emb        = (const float*)d_in[4];
  const float* w_in       = (const float*)d_in[5];
  const float* b_in       = (const float*)d_in[6];
  const float* w_out      = (const float*)d_in[7];
  const float* b_out      = (const float*)d_in[8];
  const float* b_iah      = (const float*)d_in[9];
  const float* b_oah      = (const float*)d_in[10];
  const float* wi         = (const float*)d_in[11];
  const float* bi         = (const float*)d_in[12];
  const float* wh         = (const float*)d_in[13];
  const float* bh         = (const float*)d_in[14];
  const float* w1         = (const float*)d_in[15];
  const float* b1         = (const float*)d_in[16];
  const float* w2         = (const float*)d_in[17];
  const float* b2         = (const float*)d_in[18];
  const float* wq         = (const float*)d_in[19];
  const float* w3         = (const float*)d_in[20];
  const float* b3         = (const float*)d_in[21];
  float* out = (float*)d_out;

  hipLaunchKernelGGL(srgnn_kernel, dim3(NB), dim3(BDIM), 0, stream,
                     A, items, mask, alias_in, emb,
                     w_in, b_in, w_out, b_out, b_iah, b_oah,
                     wi, bi, wh, bh, w1, b1, w2, b2, wq, w3, b3, out);
}

// Round 6
// 386.471 us; speedup vs baseline: 75.6047x; 1.4323x over previous
//
#include <hip/hip_runtime.h>
#include <stdint.h>

// SR-GNN fused kernel, R6: MFMA for GRU phases AND the attention alpha GEMM.
// One wg per batch element, 3 wg/CU. Weights stream global->reg (bf16 pack);
// q1/w3 matvecs read fp32 weights directly per-thread. No bias LDS staging.

#define BDIM 256
#define NB   1024
#define NN   64
#define HH   128
#define SH_STR 136   // u16 stride; 272B rows
#define SX_STR 264   // u16 stride; 528B rows

typedef short v8s __attribute__((ext_vector_type(8)));
typedef float v4f __attribute__((ext_vector_type(4)));

__device__ __forceinline__ float b2f_lo(uint32_t u){
  union { uint32_t u; float f; } v; v.u = u << 16; return v.f;
}
__device__ __forceinline__ float b2f_hi(uint32_t u){
  union { uint32_t u; float f; } v; v.u = u & 0xffff0000u; return v.f;
}
__device__ __forceinline__ uint16_t f2b(float f){   // RNE
  union { float f; uint32_t u; } v; v.f = f;
  uint32_t r = v.u + 0x7fffu + ((v.u >> 16) & 1u);
  return (uint16_t)(r >> 16);
}
__device__ __forceinline__ float b2f(uint16_t s){
  union { uint32_t u; float f; } v; v.u = ((uint32_t)s) << 16; return v.f;
}
__device__ __forceinline__ float sig_f(float x){ return 1.0f / (1.0f + __expf(-x)); }
__device__ __forceinline__ float tanh_f(float x){ return 1.0f - 2.0f / (__expf(2.0f*x) + 1.0f); }

// round-half-up f32->bf16 pack of two floats (a=lo16, b=hi16)
__device__ __forceinline__ uint32_t pack2bf(float a, float b){
  union { float f; uint32_t u; } ua, ub; ua.f = a; ub.f = b;
  return __builtin_amdgcn_perm(ub.u + 0x8000u, ua.u + 0x8000u, 0x07060302u);
}

// B-frag from row-major fp32 global: elem j = W[row_base+r][k_base+q*8+j]
__device__ __forceinline__ v8s ldwB(const float* __restrict__ W, int ld,
                                    int row_base, int k_base, int r, int q){
  const float* p = W + (size_t)(row_base + r) * ld + k_base + q * 8;
  float4 f0 = *reinterpret_cast<const float4*>(p);
  float4 f1 = *reinterpret_cast<const float4*>(p + 4);
  union { uint32_t u[4]; v8s v; } o;
  o.u[0] = pack2bf(f0.x, f0.y);
  o.u[1] = pack2bf(f0.z, f0.w);
  o.u[2] = pack2bf(f1.x, f1.y);
  o.u[3] = pack2bf(f1.z, f1.w);
  return o.v;
}

// A-frag from LDS bf16 row-major: elem j = buf[row_base+r][k_base+q*8+j]
__device__ __forceinline__ v8s ldsA(const uint16_t* buf, int stride,
                                    int row_base, int k_base, int r, int q){
  return *reinterpret_cast<const v8s*>(&buf[(row_base + r) * stride + k_base + q * 8]);
}

#define MFMA(a, b, c) __builtin_amdgcn_mfma_f32_16x16x32_bf16((a), (b), (c), 0, 0, 0)

__global__ __launch_bounds__(BDIM, 3) void srgnn_kernel(
    const float* __restrict__ A,
    const int*   __restrict__ items,
    const int*   __restrict__ mask,
    const int*   __restrict__ alias_input,
    const float* __restrict__ emb,
    const float* __restrict__ w_in,  const float* __restrict__ b_in,
    const float* __restrict__ w_out, const float* __restrict__ b_out,
    const float* __restrict__ b_iah, const float* __restrict__ b_oah,
    const float* __restrict__ wi,    const float* __restrict__ bi,
    const float* __restrict__ wh,    const float* __restrict__ bh,
    const float* __restrict__ w1,    const float* __restrict__ b1,
    const float* __restrict__ w2,    const float* __restrict__ b2,
    const float* __restrict__ wq,
    const float* __restrict__ w3,    const float* __restrict__ b3,
    float* __restrict__ out)
{
  __shared__ __align__(16) uint16_t sH[NN * SH_STR];   // hidden bf16, 17.0 KB
  __shared__ __align__(16) uint16_t sX[NN * SX_STR];   // h_in|h_out -> ie, 33.0 KB
  __shared__ float sQ1[128], sGlob[128], sAPart[4][64], sAlpha[64];
  __shared__ int   sAliasRow[64], sMaskArr[64];

  const int t    = threadIdx.x;
  const int b    = blockIdx.x;
  const int lane = t & 63;
  const int wv   = __builtin_amdgcn_readfirstlane(t >> 6);
  const int r    = lane & 15;
  const int q    = lane >> 4;

  // ---------- P0: embeddings + alias/mask ----------
  {
    const int* itb = items + b * NN;
    for (int j = t; j < NN * HH; j += BDIM) {
      int n = j >> 7, k = j & 127;
      sH[n * SH_STR + k] = f2b(emb[(size_t)itb[n] * HH + k]);
    }
    if (t < 64) {
      sAliasRow[t] = alias_input[b * 64 + t];
      sMaskArr[t]  = mask[b * 64 + t];
    }
  }
  __syncthreads();

  for (int step = 0; step < 2; ++step) {
    // ---------- P1 (MFMA): sX[n][c] = bias[c] + sum_k H[n][k]*W[c][k] ----------
    {
      v8s a[4][4];
      #pragma unroll
      for (int mt = 0; mt < 4; ++mt)
        #pragma unroll
        for (int kk = 0; kk < 4; ++kk)
          a[mt][kk] = ldsA(sH, SH_STR, mt * 16, kk * 32, r, q);

      const float* Wsel = (wv < 2) ? w_in : w_out;
      const float* bsel = (wv < 2) ? b_in : b_out;
      const int    wofs = (wv < 2) ? 0 : 128;
      #pragma unroll 1
      for (int i = 0; i < 4; ++i) {
        int nt = wv * 4 + i;
        int c  = nt * 16 + r;
        float bini = bsel[c - wofs];
        v4f acc0 = {bini, bini, bini, bini}, acc1 = acc0, acc2 = acc0, acc3 = acc0;
        #pragma unroll
        for (int kk = 0; kk < 4; ++kk) {
          v8s bf = ldwB(Wsel, 128, nt * 16 - wofs, kk * 32, r, q);
          acc0 = MFMA(a[0][kk], bf, acc0);
          acc1 = MFMA(a[1][kk], bf, acc1);
          acc2 = MFMA(a[2][kk], bf, acc2);
          acc3 = MFMA(a[3][kk], bf, acc3);
        }
        #pragma unroll
        for (int reg = 0; reg < 4; ++reg) {
          sX[(0  + q * 4 + reg) * SX_STR + c] = f2b(acc0[reg]);
          sX[(16 + q * 4 + reg) * SX_STR + c] = f2b(acc1[reg]);
          sX[(32 + q * 4 + reg) * SX_STR + c] = f2b(acc2[reg]);
          sX[(48 + q * 4 + reg) * SX_STR + c] = f2b(acc3[reg]);
        }
      }
    }
    // no barrier: each wave reads back only its own columns in P2

    // ---------- P2 (MFMA): ie[n][c] = bias[c] + sum_m Adj[n][m]*X[m][c] ----
    {
      const int half = wv >> 1;
      v8s a2[4][2];
      #pragma unroll
      for (int mt = 0; mt < 4; ++mt)
        #pragma unroll
        for (int kk = 0; kk < 2; ++kk) {
          const float* p = A + (size_t)(b * NN + mt * 16 + r) * (2 * NN)
                             + half * 64 + kk * 32 + q * 8;
          float4 f0 = *reinterpret_cast<const float4*>(p);
          float4 f1 = *reinterpret_cast<const float4*>(p + 4);
          union { uint32_t u[4]; v8s v; } o;
          o.u[0] = pack2bf(f0.x, f0.y); o.u[1] = pack2bf(f0.z, f0.w);
          o.u[2] = pack2bf(f1.x, f1.y); o.u[3] = pack2bf(f1.z, f1.w);
          a2[mt][kk] = o.v;
        }
      const float* bsel2 = (wv < 2) ? b_iah : b_oah;
      const int    wofs2 = (wv < 2) ? 0 : 128;
      #pragma unroll 1
      for (int i = 0; i < 4; ++i) {
        int nt = wv * 4 + i;
        int c  = nt * 16 + r;
        v8s b0, b1f;
        #pragma unroll
        for (int j = 0; j < 8; ++j) {
          b0[j]  = (short)sX[(q * 8 + j) * SX_STR + c];
          b1f[j] = (short)sX[(32 + q * 8 + j) * SX_STR + c];
        }
        float bini = bsel2[c - wofs2];
        v4f acc0 = {bini, bini, bini, bini}, acc1 = acc0, acc2 = acc0, acc3 = acc0;
        acc0 = MFMA(a2[0][0], b0, acc0); acc0 = MFMA(a2[0][1], b1f, acc0);
        acc1 = MFMA(a2[1][0], b0, acc1); acc1 = MFMA(a2[1][1], b1f, acc1);
        acc2 = MFMA(a2[2][0], b0, acc2); acc2 = MFMA(a2[2][1], b1f, acc2);
        acc3 = MFMA(a2[3][0], b0, acc3); acc3 = MFMA(a2[3][1], b1f, acc3);
        #pragma unroll
        for (int reg = 0; reg < 4; ++reg) {
          sX[(0  + q * 4 + reg) * SX_STR + c] = f2b(acc0[reg]);
          sX[(16 + q * 4 + reg) * SX_STR + c] = f2b(acc1[reg]);
          sX[(32 + q * 4 + reg) * SX_STR + c] = f2b(acc2[reg]);
          sX[(48 + q * 4 + reg) * SX_STR + c] = f2b(acc3[reg]);
        }
      }
    }
    __syncthreads();

    // ---------- P3 (MFMA): gates over h-cols [wv*32, wv*32+32) ----------
    {
      const int h0 = wv * 32;
      v4f aR[2][4], aI[2][4], aNi[2][4], aNh[2][4];
      #pragma unroll
      for (int u = 0; u < 2; ++u) {
        int h = h0 + u * 16 + r;
        float vR  = bi[h] + bh[h];
        float vI  = bi[128 + h] + bh[128 + h];
        float vNi = bi[256 + h];
        float vNh = bh[256 + h];
        #pragma unroll
        for (int mt = 0; mt < 4; ++mt) {
          aR[u][mt]  = (v4f){vR, vR, vR, vR};
          aI[u][mt]  = (v4f){vI, vI, vI, vI};
          aNi[u][mt] = (v4f){vNi, vNi, vNi, vNi};
          aNh[u][mt] = (v4f){vNh, vNh, vNh, vNh};
        }
      }
      // gi: IE[64x256] @ wi^T
      #pragma unroll 1
      for (int kk = 0; kk < 8; ++kk) {
        v8s af0 = ldsA(sX, SX_STR, 0,  kk * 32, r, q);
        v8s af1 = ldsA(sX, SX_STR, 16, kk * 32, r, q);
        v8s af2 = ldsA(sX, SX_STR, 32, kk * 32, r, q);
        v8s af3 = ldsA(sX, SX_STR, 48, kk * 32, r, q);
        #pragma unroll
        for (int u = 0; u < 2; ++u) {
          int wr = h0 + u * 16;
          v8s bR = ldwB(wi, 256, wr,        kk * 32, r, q);
          v8s bI = ldwB(wi, 256, 128 + wr,  kk * 32, r, q);
          v8s bN = ldwB(wi, 256, 256 + wr,  kk * 32, r, q);
          aR[u][0]  = MFMA(af0, bR, aR[u][0]);  aR[u][1]  = MFMA(af1, bR, aR[u][1]);
          aR[u][2]  = MFMA(af2, bR, aR[u][2]);  aR[u][3]  = MFMA(af3, bR, aR[u][3]);
          aI[u][0]  = MFMA(af0, bI, aI[u][0]);  aI[u][1]  = MFMA(af1, bI, aI[u][1]);
          aI[u][2]  = MFMA(af2, bI, aI[u][2]);  aI[u][3]  = MFMA(af3, bI, aI[u][3]);
          aNi[u][0] = MFMA(af0, bN, aNi[u][0]); aNi[u][1] = MFMA(af1, bN, aNi[u][1]);
          aNi[u][2] = MFMA(af2, bN, aNi[u][2]); aNi[u][3] = MFMA(af3, bN, aNi[u][3]);
        }
      }
      // gh: H[64x128] @ wh^T
      #pragma unroll 1
      for (int kk = 0; kk < 4; ++kk) {
        v8s af0 = ldsA(sH, SH_STR, 0,  kk * 32, r, q);
        v8s af1 = ldsA(sH, SH_STR, 16, kk * 32, r, q);
        v8s af2 = ldsA(sH, SH_STR, 32, kk * 32, r, q);
        v8s af3 = ldsA(sH, SH_STR, 48, kk * 32, r, q);
        #pragma unroll
        for (int u = 0; u < 2; ++u) {
          int wr = h0 + u * 16;
          v8s bR = ldwB(wh, 128, wr,        kk * 32, r, q);
          v8s bI = ldwB(wh, 128, 128 + wr,  kk * 32, r, q);
          v8s bN = ldwB(wh, 128, 256 + wr,  kk * 32, r, q);
          aR[u][0]  = MFMA(af0, bR, aR[u][0]);  aR[u][1]  = MFMA(af1, bR, aR[u][1]);
          aR[u][2]  = MFMA(af2, bR, aR[u][2]);  aR[u][3]  = MFMA(af3, bR, aR[u][3]);
          aI[u][0]  = MFMA(af0, bI, aI[u][0]);  aI[u][1]  = MFMA(af1, bI, aI[u][1]);
          aI[u][2]  = MFMA(af2, bI, aI[u][2]);  aI[u][3]  = MFMA(af3, bI, aI[u][3]);
          aNh[u][0] = MFMA(af0, bN, aNh[u][0]); aNh[u][1] = MFMA(af1, bN, aNh[u][1]);
          aNh[u][2] = MFMA(af2, bN, aNh[u][2]); aNh[u][3] = MFMA(af3, bN, aNh[u][3]);
        }
      }
      __syncthreads();   // all sX/sH fragment reads done before sH overwrite

      #pragma unroll
      for (int u = 0; u < 2; ++u) {
        int h = h0 + u * 16 + r;
        #pragma unroll
        for (int mt = 0; mt < 4; ++mt) {
          #pragma unroll
          for (int reg = 0; reg < 4; ++reg) {
            int row = mt * 16 + q * 4 + reg;
            float z  = sig_f(aI[u][mt][reg]);
            float rr = sig_f(aR[u][mt][reg]);
            float gg = tanh_f(fmaf(rr, aNh[u][mt][reg], aNi[u][mt][reg]));
            float hp = b2f(sH[row * SH_STR + h]);
            sH[row * SH_STR + h] = f2b(fmaf(z, gg - hp, hp));
          }
        }
      }
    }
    __syncthreads();
  }

  // ---------- P4: attention readout ----------
  int msum = 0;
  #pragma unroll
  for (int l = 0; l < 64; ++l) msum += sMaskArr[l];
  const int lastRow = sAliasRow[msum - 1];

  // q1[t] = b1[t] + dot(local, w1[t]) — fp32 weights direct from global
  if (t < HH) {
    const float4* w14 = reinterpret_cast<const float4*>(w1 + (size_t)t * HH);
    const uint2*  lr  = reinterpret_cast<const uint2*>(&sH[lastRow * SH_STR]);
    float a0 = b1[t], a1 = 0.f, a2 = 0.f, a3 = 0.f;
    #pragma unroll 8
    for (int j = 0; j < 32; ++j) {
      float4 w = w14[j]; uint2 v = lr[j];
      a0 = fmaf(b2f_lo(v.x), w.x, a0); a1 = fmaf(b2f_hi(v.x), w.y, a1);
      a2 = fmaf(b2f_lo(v.y), w.z, a2); a3 = fmaf(b2f_hi(v.y), w.w, a3);
    }
    sQ1[t] = (a0 + a1) + (a2 + a3);
  }
  __syncthreads();

  // alpha (MFMA): S[l][h] = q1[h]+b2[h] + seq[l]·w2[h];
  // wave wv covers h in [wv*32, wv*32+32)
  {
    v8s a[4][4];
    #pragma unroll
    for (int mt = 0; mt < 4; ++mt) {
      int row = sAliasRow[mt * 16 + r];
      #pragma unroll
      for (int kk = 0; kk < 4; ++kk)
        a[mt][kk] = *reinterpret_cast<const v8s*>(&sH[row * SH_STR + kk * 32 + q * 8]);
    }
    float part[16];
    #pragma unroll
    for (int i = 0; i < 16; ++i) part[i] = 0.f;
    #pragma unroll 1
    for (int u = 0; u < 2; ++u) {
      int hb = wv * 32 + u * 16;
      int h  = hb + r;
      float binit = sQ1[h] + b2[h];
      v4f acc[4];
      #pragma unroll
      for (int mt = 0; mt < 4; ++mt) acc[mt] = (v4f){binit, binit, binit, binit};
      #pragma unroll
      for (int kk = 0; kk < 4; ++kk) {
        v8s bf = ldwB(w2, 128, hb, kk * 32, r, q);
        acc[0] = MFMA(a[0][kk], bf, acc[0]);
        acc[1] = MFMA(a[1][kk], bf, acc[1]);
        acc[2] = MFMA(a[2][kk], bf, acc[2]);
        acc[3] = MFMA(a[3][kk], bf, acc[3]);
      }
      float wqh = wq[h];
      #pragma unroll
      for (int mt = 0; mt < 4; ++mt)
        #pragma unroll
        for (int reg = 0; reg < 4; ++reg)
          part[mt * 4 + reg] += sig_f(acc[mt][reg]) * wqh;
    }
    // reduce over the 16 r-lanes (lane bits 0..3)
    #pragma unroll
    for (int m = 1; m <= 8; m <<= 1)
      #pragma unroll
      for (int i = 0; i < 16; ++i)
        part[i] += __shfl_xor(part[i], m);
    if (r == 0) {
      #pragma unroll
      for (int mt = 0; mt < 4; ++mt)
        #pragma unroll
        for (int reg = 0; reg < 4; ++reg)
          sAPart[wv][mt * 16 + q * 4 + reg] = part[mt * 4 + reg];
    }
  }
  __syncthreads();
  if (t < 64) {
    sAlpha[t] = (sAPart[0][t] + sAPart[1][t] + sAPart[2][t] + sAPart[3][t])
              * (float)sMaskArr[t];
  }
  __syncthreads();
  if (t < HH) {
    float acc = 0.0f;
    #pragma unroll
    for (int l = 0; l < 64; ++l)
      acc = fmaf(sAlpha[l], b2f(sH[sAliasRow[l] * SH_STR + t]), acc);
    sGlob[t] = acc;
  }
  __syncthreads();
  // out[t] = b3[t] + local·w3[t][:128] + glob·w3[t][128:] — fp32 direct
  if (t < HH) {
    const float4* w34 = reinterpret_cast<const float4*>(w3 + (size_t)t * 256);
    const uint2*  lr  = reinterpret_cast<const uint2*>(&sH[lastRow * SH_STR]);
    float a0 = b3[t], a1 = 0.f, a2 = 0.f, a3 = 0.f;
    #pragma unroll 8
    for (int j = 0; j < 32; ++j) {
      float4 w = w34[j]; uint2 v = lr[j];
      a0 = fmaf(b2f_lo(v.x), w.x, a0); a1 = fmaf(b2f_hi(v.x), w.y, a1);
      a2 = fmaf(b2f_lo(v.y), w.z, a2); a3 = fmaf(b2f_hi(v.y), w.w, a3);
    }
    const float4* w34b = w34 + 32;
    #pragma unroll 8
    for (int j = 0; j < 32; ++j) {
      float4 w = w34b[j];
      a0 = fmaf(sGlob[4*j+0], w.x, a0); a1 = fmaf(sGlob[4*j+1], w.y, a1);
      a2 = fmaf(sGlob[4*j+2], w.z, a2); a3 = fmaf(sGlob[4*j+3], w.w, a3);
    }
    out[b * HH + t] = (a0 + a1) + (a2 + a3);
  }
}

extern "C" void kernel_launch(void* const* d_in, const int* in_sizes, int n_in,
                              void* d_out, int out_size, void* d_ws, size_t ws_size,
                              hipStream_t stream) {
  const float* A          = (const float*)d_in[0];
  const int*   items      = (const int*)  d_in[1];
  const int*   mask       = (const int*)  d_in[2];
  const int*   alias_in   = (const int*)  d_in[3];
  const float* emb        = (const float*)d_in[4];
  const float* w_in       = (const float*)d_in[5];
  const float* b_in       = (const float*)d_in[6];
  const float* w_out      = (const float*)d_in[7];
  const float* b_out      = (const float*)d_in[8];
  const float* b_iah      = (const float*)d_in[9];
  const float* b_oah      = (const float*)d_in[10];
  const float* wi         = (const float*)d_in[11];
  const float* bi         = (const float*)d_in[12];
  const float* wh         = (const float*)d_in[13];
  const float* bh         = (const float*)d_in[14];
  const float* w1         = (const float*)d_in[15];
  const float* b1         = (const float*)d_in[16];
  const float* w2         = (const float*)d_in[17];
  const float* b2         = (const float*)d_in[18];
  const float* wq         = (const float*)d_in[19];
  const float* w3         = (const float*)d_in[20];
  const float* b3         = (const float*)d_in[21];
  float* out = (float*)d_out;

  hipLaunchKernelGGL(srgnn_kernel, dim3(NB), dim3(BDIM), 0, stream,
                     A, items, mask, alias_in, emb,
                     w_in, b_in, w_out, b_out, b_iah, b_oah,
                     wi, bi, wh, bh, w1, b1, w2, b2, wq, w3, b3, out);
}

// Round 7
// 286.451 us; speedup vs baseline: 102.0034x; 1.3492x over previous
//
#include <hip/hip_runtime.h>
#include <stdint.h>

// SR-GNN fused, R7: weights pre-packed fp32->bf16 into d_ws in MFMA B-frag
// order by a tiny pre-pass kernel. Main kernel loads each B-frag with a single
// coalesced global_load_dwordx4 (no pack VALU, deep pipelining). A-fragments
// hoisted before the step loop (step-invariant). R6 latency-bound diagnosis:
// MfmaUtil 7%, VALUBusy 22%, occ 23% -> stalls on per-iteration weight loads.

#define BDIM 256
#define NB   1024
#define NN   64
#define HH   128
#define SH_STR 136   // u16 stride; 272B rows
#define SX_STR 264   // u16 stride; 528B rows

// d_ws fragment-layout offsets (u16 units)
#define OFS_WIN  0         // w_in : 8 tr x 4 kc x 64 lanes x 8  = 16384
#define OFS_WOUT 16384     // w_out: 16384
#define OFS_WI   32768     // wi   : 24 tr x 8 kc x 64 x 8       = 98304
#define OFS_WH   131072    // wh   : 24 tr x 4 kc x 64 x 8       = 49152
#define OFS_W2   180224    // w2   : 8 tr x 4 kc x 64 x 8        = 16384
#define N_FRAGS  24576     // total frags (16B each) = 384 KB

typedef short v8s __attribute__((ext_vector_type(8)));
typedef float v4f __attribute__((ext_vector_type(4)));

__device__ __forceinline__ float b2f_lo(uint32_t u){
  union { uint32_t u; float f; } v; v.u = u << 16; return v.f;
}
__device__ __forceinline__ float b2f_hi(uint32_t u){
  union { uint32_t u; float f; } v; v.u = u & 0xffff0000u; return v.f;
}
__device__ __forceinline__ uint16_t f2b(float f){   // RNE
  union { float f; uint32_t u; } v; v.f = f;
  uint32_t r = v.u + 0x7fffu + ((v.u >> 16) & 1u);
  return (uint16_t)(r >> 16);
}
__device__ __forceinline__ float b2f(uint16_t s){
  union { uint32_t u; float f; } v; v.u = ((uint32_t)s) << 16; return v.f;
}
__device__ __forceinline__ float sig_f(float x){ return 1.0f / (1.0f + __expf(-x)); }
__device__ __forceinline__ float tanh_f(float x){ return 1.0f - 2.0f / (__expf(2.0f*x) + 1.0f); }

// round-half-up f32->bf16 pack of two floats (a=lo16, b=hi16)
__device__ __forceinline__ uint32_t pack2bf(float a, float b){
  union { float f; uint32_t u; } ua, ub; ua.f = a; ub.f = b;
  return __builtin_amdgcn_perm(ub.u + 0x8000u, ua.u + 0x8000u, 0x07060302u);
}

__device__ __forceinline__ v8s pack8(const float* __restrict__ p){
  float4 f0 = *reinterpret_cast<const float4*>(p);
  float4 f1 = *reinterpret_cast<const float4*>(p + 4);
  union { uint32_t u[4]; v8s v; } o;
  o.u[0] = pack2bf(f0.x, f0.y);
  o.u[1] = pack2bf(f0.z, f0.w);
  o.u[2] = pack2bf(f1.x, f1.y);
  o.u[3] = pack2bf(f1.z, f1.w);
  return o.v;
}

// A-frag from LDS bf16 row-major
__device__ __forceinline__ v8s ldsA(const uint16_t* buf, int stride,
                                    int row_base, int k_base, int r, int q){
  return *reinterpret_cast<const v8s*>(&buf[(row_base + r) * stride + k_base + q * 8]);
}

// pre-packed B-frag: one coalesced 16B load
__device__ __forceinline__ v8s ldfrag(const uint16_t* __restrict__ ws,
                                      int base, int tile, int lane){
  return *reinterpret_cast<const v8s*>(ws + base + (((size_t)tile * 64 + lane) << 3));
}

#define MFMA(a, b, c) __builtin_amdgcn_mfma_f32_16x16x32_bf16((a), (b), (c), 0, 0, 0)

// ---------------- pre-pass: pack weights into frag layout ----------------
__global__ __launch_bounds__(256) void pack_weights(
    const float* __restrict__ w_in, const float* __restrict__ w_out,
    const float* __restrict__ wi,   const float* __restrict__ wh,
    const float* __restrict__ w2,   uint16_t* __restrict__ ws)
{
  int gid = blockIdx.x * blockDim.x + threadIdx.x;
  if (gid >= N_FRAGS) return;
  const float* W; int C; int fi; int base;
  if (gid < 2048)       { W = w_in;  C = 128; fi = gid;         base = OFS_WIN; }
  else if (gid < 4096)  { W = w_out; C = 128; fi = gid - 2048;  base = OFS_WOUT; }
  else if (gid < 16384) { W = wi;    C = 256; fi = gid - 4096;  base = OFS_WI; }
  else if (gid < 22528) { W = wh;    C = 128; fi = gid - 16384; base = OFS_WH; }
  else                  { W = w2;    C = 128; fi = gid - 22528; base = OFS_W2; }
  int lane = fi & 63;
  int tile = fi >> 6;            // tr * (C/32) + kc
  int tc   = C >> 5;
  int tr   = tile / tc, kc = tile - tr * tc;
  int r = lane & 15, q = lane >> 4;
  const float* p = W + (size_t)(tr * 16 + r) * C + kc * 32 + q * 8;
  *reinterpret_cast<v8s*>(ws + base + ((size_t)fi << 3)) = pack8(p);
}

// ---------------- main kernel ----------------
__global__ __launch_bounds__(BDIM, 3) void srgnn_kernel(
    const float* __restrict__ A,
    const int*   __restrict__ items,
    const int*   __restrict__ mask,
    const int*   __restrict__ alias_input,
    const float* __restrict__ emb,
    const float* __restrict__ b_in,  const float* __restrict__ b_out,
    const float* __restrict__ b_iah, const float* __restrict__ b_oah,
    const float* __restrict__ bi,    const float* __restrict__ bh,
    const float* __restrict__ w1,    const float* __restrict__ b1,
    const float* __restrict__ b2,
    const float* __restrict__ wq,
    const float* __restrict__ w3,    const float* __restrict__ b3,
    const uint16_t* __restrict__ ws,
    float* __restrict__ out)
{
  __shared__ __align__(16) uint16_t sH[NN * SH_STR];   // hidden bf16, 17.0 KB
  __shared__ __align__(16) uint16_t sX[NN * SX_STR];   // h_in|h_out -> ie, 33.0 KB
  __shared__ float sQ1[128], sGlob[128], sAPart[4][64], sAlpha[64];
  __shared__ int   sAliasRow[64], sMaskArr[64];

  const int t    = threadIdx.x;
  const int b    = blockIdx.x;
  const int lane = t & 63;
  const int wv   = __builtin_amdgcn_readfirstlane(t >> 6);
  const int r    = lane & 15;
  const int q    = lane >> 4;

  // ---------- P0: embeddings + alias/mask; hoisted A-fragments ----------
  {
    const int* itb = items + b * NN;
    for (int j = t; j < NN * HH; j += BDIM) {
      int n = j >> 7, k = j & 127;
      sH[n * SH_STR + k] = f2b(emb[(size_t)itb[n] * HH + k]);
    }
    if (t < 64) {
      sAliasRow[t] = alias_input[b * 64 + t];
      sMaskArr[t]  = mask[b * 64 + t];
    }
  }

  // A-fragments: step-invariant, load+pack once (wave's half of A)
  v8s a2[4][2];
  {
    const int half = wv >> 1;
    #pragma unroll
    for (int mt = 0; mt < 4; ++mt)
      #pragma unroll
      for (int kk = 0; kk < 2; ++kk)
        a2[mt][kk] = pack8(A + (size_t)(b * NN + mt * 16 + r) * (2 * NN)
                             + half * 64 + kk * 32 + q * 8);
  }
  __syncthreads();

  for (int step = 0; step < 2; ++step) {
    // ---------- P1 (MFMA): sX[n][c] = bias[c] + sum_k H[n][k]*W[c][k] ----------
    {
      v8s a[4][4];
      #pragma unroll
      for (int mt = 0; mt < 4; ++mt)
        #pragma unroll
        for (int kk = 0; kk < 4; ++kk)
          a[mt][kk] = ldsA(sH, SH_STR, mt * 16, kk * 32, r, q);

      const int    wbase = (wv < 2) ? OFS_WIN : OFS_WOUT;
      const float* bsel  = (wv < 2) ? b_in : b_out;
      const int    ntofs = (wv < 2) ? 0 : 8;
      #pragma unroll 2
      for (int i = 0; i < 4; ++i) {
        int nt = wv * 4 + i;
        int tr = nt - ntofs;
        int c  = nt * 16 + r;
        float bini = bsel[tr * 16 + r];
        v4f acc0 = {bini, bini, bini, bini}, acc1 = acc0, acc2 = acc0, acc3 = acc0;
        #pragma unroll
        for (int kk = 0; kk < 4; ++kk) {
          v8s bf = ldfrag(ws, wbase, tr * 4 + kk, lane);
          acc0 = MFMA(a[0][kk], bf, acc0);
          acc1 = MFMA(a[1][kk], bf, acc1);
          acc2 = MFMA(a[2][kk], bf, acc2);
          acc3 = MFMA(a[3][kk], bf, acc3);
        }
        #pragma unroll
        for (int reg = 0; reg < 4; ++reg) {
          sX[(0  + q * 4 + reg) * SX_STR + c] = f2b(acc0[reg]);
          sX[(16 + q * 4 + reg) * SX_STR + c] = f2b(acc1[reg]);
          sX[(32 + q * 4 + reg) * SX_STR + c] = f2b(acc2[reg]);
          sX[(48 + q * 4 + reg) * SX_STR + c] = f2b(acc3[reg]);
        }
      }
    }
    // no barrier: each wave reads back only its own columns in P2

    // ---------- P2 (MFMA): ie[n][c] = bias[c] + sum_m Adj[n][m]*X[m][c] ----
    {
      const float* bsel2 = (wv < 2) ? b_iah : b_oah;
      const int    wofs2 = (wv < 2) ? 0 : 128;
      #pragma unroll 1
      for (int i = 0; i < 4; ++i) {
        int nt = wv * 4 + i;
        int c  = nt * 16 + r;
        v8s b0, b1f;
        #pragma unroll
        for (int j = 0; j < 8; ++j) {
          b0[j]  = (short)sX[(q * 8 + j) * SX_STR + c];
          b1f[j] = (short)sX[(32 + q * 8 + j) * SX_STR + c];
        }
        float bini = bsel2[c - wofs2];
        v4f acc0 = {bini, bini, bini, bini}, acc1 = acc0, acc2 = acc0, acc3 = acc0;
        acc0 = MFMA(a2[0][0], b0, acc0); acc0 = MFMA(a2[0][1], b1f, acc0);
        acc1 = MFMA(a2[1][0], b0, acc1); acc1 = MFMA(a2[1][1], b1f, acc1);
        acc2 = MFMA(a2[2][0], b0, acc2); acc2 = MFMA(a2[2][1], b1f, acc2);
        acc3 = MFMA(a2[3][0], b0, acc3); acc3 = MFMA(a2[3][1], b1f, acc3);
        #pragma unroll
        for (int reg = 0; reg < 4; ++reg) {
          sX[(0  + q * 4 + reg) * SX_STR + c] = f2b(acc0[reg]);
          sX[(16 + q * 4 + reg) * SX_STR + c] = f2b(acc1[reg]);
          sX[(32 + q * 4 + reg) * SX_STR + c] = f2b(acc2[reg]);
          sX[(48 + q * 4 + reg) * SX_STR + c] = f2b(acc3[reg]);
        }
      }
    }
    __syncthreads();

    // ---------- P3 (MFMA): gates over h-cols [wv*32, wv*32+32) ----------
    {
      const int h0 = wv * 32;
      v4f aR[2][4], aI[2][4], aNi[2][4], aNh[2][4];
      #pragma unroll
      for (int u = 0; u < 2; ++u) {
        int h = h0 + u * 16 + r;
        float vR  = bi[h] + bh[h];
        float vI  = bi[128 + h] + bh[128 + h];
        float vNi = bi[256 + h];
        float vNh = bh[256 + h];
        #pragma unroll
        for (int mt = 0; mt < 4; ++mt) {
          aR[u][mt]  = (v4f){vR, vR, vR, vR};
          aI[u][mt]  = (v4f){vI, vI, vI, vI};
          aNi[u][mt] = (v4f){vNi, vNi, vNi, vNi};
          aNh[u][mt] = (v4f){vNh, vNh, vNh, vNh};
        }
      }
      // gi: IE[64x256] @ wi^T   (wi frags: tr = g*8 + wv*2 + u, tc=8)
      #pragma unroll 2
      for (int kk = 0; kk < 8; ++kk) {
        v8s af0 = ldsA(sX, SX_STR, 0,  kk * 32, r, q);
        v8s af1 = ldsA(sX, SX_STR, 16, kk * 32, r, q);
        v8s af2 = ldsA(sX, SX_STR, 32, kk * 32, r, q);
        v8s af3 = ldsA(sX, SX_STR, 48, kk * 32, r, q);
        #pragma unroll
        for (int u = 0; u < 2; ++u) {
          int trb = wv * 2 + u;
          v8s bR = ldfrag(ws, OFS_WI, (0 * 8 + trb) * 8 + kk, lane);
          v8s bI = ldfrag(ws, OFS_WI, (8 + trb) * 8 + kk, lane);
          v8s bN = ldfrag(ws, OFS_WI, (16 + trb) * 8 + kk, lane);
          aR[u][0]  = MFMA(af0, bR, aR[u][0]);  aR[u][1]  = MFMA(af1, bR, aR[u][1]);
          aR[u][2]  = MFMA(af2, bR, aR[u][2]);  aR[u][3]  = MFMA(af3, bR, aR[u][3]);
          aI[u][0]  = MFMA(af0, bI, aI[u][0]);  aI[u][1]  = MFMA(af1, bI, aI[u][1]);
          aI[u][2]  = MFMA(af2, bI, aI[u][2]);  aI[u][3]  = MFMA(af3, bI, aI[u][3]);
          aNi[u][0] = MFMA(af0, bN, aNi[u][0]); aNi[u][1] = MFMA(af1, bN, aNi[u][1]);
          aNi[u][2] = MFMA(af2, bN, aNi[u][2]); aNi[u][3] = MFMA(af3, bN, aNi[u][3]);
        }
      }
      // gh: H[64x128] @ wh^T   (wh frags: tr = g*8 + wv*2 + u, tc=4)
      #pragma unroll 2
      for (int kk = 0; kk < 4; ++kk) {
        v8s af0 = ldsA(sH, SH_STR, 0,  kk * 32, r, q);
        v8s af1 = ldsA(sH, SH_STR, 16, kk * 32, r, q);
        v8s af2 = ldsA(sH, SH_STR, 32, kk * 32, r, q);
        v8s af3 = ldsA(sH, SH_STR, 48, kk * 32, r, q);
        #pragma unroll
        for (int u = 0; u < 2; ++u) {
          int trb = wv * 2 + u;
          v8s bR = ldfrag(ws, OFS_WH, (0 * 8 + trb) * 4 + kk, lane);
          v8s bI = ldfrag(ws, OFS_WH, (8 + trb) * 4 + kk, lane);
          v8s bN = ldfrag(ws, OFS_WH, (16 + trb) * 4 + kk, lane);
          aR[u][0]  = MFMA(af0, bR, aR[u][0]);  aR[u][1]  = MFMA(af1, bR, aR[u][1]);
          aR[u][2]  = MFMA(af2, bR, aR[u][2]);  aR[u][3]  = MFMA(af3, bR, aR[u][3]);
          aI[u][0]  = MFMA(af0, bI, aI[u][0]);  aI[u][1]  = MFMA(af1, bI, aI[u][1]);
          aI[u][2]  = MFMA(af2, bI, aI[u][2]);  aI[u][3]  = MFMA(af3, bI, aI[u][3]);
          aNh[u][0] = MFMA(af0, bN, aNh[u][0]); aNh[u][1] = MFMA(af1, bN, aNh[u][1]);
          aNh[u][2] = MFMA(af2, bN, aNh[u][2]); aNh[u][3] = MFMA(af3, bN, aNh[u][3]);
        }
      }
      __syncthreads();   // all sX/sH fragment reads done before sH overwrite

      #pragma unroll
      for (int u = 0; u < 2; ++u) {
        int h = h0 + u * 16 + r;
        #pragma unroll
        for (int mt = 0; mt < 4; ++mt) {
          #pragma unroll
          for (int reg = 0; reg < 4; ++reg) {
            int row = mt * 16 + q * 4 + reg;
            float z  = sig_f(aI[u][mt][reg]);
            float rr = sig_f(aR[u][mt][reg]);
            float gg = tanh_f(fmaf(rr, aNh[u][mt][reg], aNi[u][mt][reg]));
            float hp = b2f(sH[row * SH_STR + h]);
            sH[row * SH_STR + h] = f2b(fmaf(z, gg - hp, hp));
          }
        }
      }
    }
    __syncthreads();
  }

  // ---------- P4: attention readout ----------
  int msum = 0;
  #pragma unroll
  for (int l = 0; l < 64; ++l) msum += sMaskArr[l];
  const int lastRow = sAliasRow[msum - 1];

  // q1[t] = b1[t] + dot(local, w1[t]) — fp32 weights direct
  if (t < HH) {
    const float4* w14 = reinterpret_cast<const float4*>(w1 + (size_t)t * HH);
    const uint2*  lr  = reinterpret_cast<const uint2*>(&sH[lastRow * SH_STR]);
    float a0 = b1[t], a1 = 0.f, a2v = 0.f, a3 = 0.f;
    #pragma unroll 8
    for (int j = 0; j < 32; ++j) {
      float4 w = w14[j]; uint2 v = lr[j];
      a0  = fmaf(b2f_lo(v.x), w.x, a0);  a1 = fmaf(b2f_hi(v.x), w.y, a1);
      a2v = fmaf(b2f_lo(v.y), w.z, a2v); a3 = fmaf(b2f_hi(v.y), w.w, a3);
    }
    sQ1[t] = (a0 + a1) + (a2v + a3);
  }
  __syncthreads();

  // alpha (MFMA): wave wv covers h in [wv*32, wv*32+32)
  {
    v8s a[4][4];
    #pragma unroll
    for (int mt = 0; mt < 4; ++mt) {
      int row = sAliasRow[mt * 16 + r];
      #pragma unroll
      for (int kk = 0; kk < 4; ++kk)
        a[mt][kk] = *reinterpret_cast<const v8s*>(&sH[row * SH_STR + kk * 32 + q * 8]);
    }
    float part[16];
    #pragma unroll
    for (int i = 0; i < 16; ++i) part[i] = 0.f;
    #pragma unroll
    for (int u = 0; u < 2; ++u) {
      int h = wv * 32 + u * 16 + r;
      float binit = sQ1[h] + b2[h];
      v4f acc[4];
      #pragma unroll
      for (int mt = 0; mt < 4; ++mt) acc[mt] = (v4f){binit, binit, binit, binit};
      #pragma unroll
      for (int kk = 0; kk < 4; ++kk) {
        v8s bf = ldfrag(ws, OFS_W2, (wv * 2 + u) * 4 + kk, lane);
        acc[0] = MFMA(a[0][kk], bf, acc[0]);
        acc[1] = MFMA(a[1][kk], bf, acc[1]);
        acc[2] = MFMA(a[2][kk], bf, acc[2]);
        acc[3] = MFMA(a[3][kk], bf, acc[3]);
      }
      float wqh = wq[h];
      #pragma unroll
      for (int mt = 0; mt < 4; ++mt)
        #pragma unroll
        for (int reg = 0; reg < 4; ++reg)
          part[mt * 4 + reg] += sig_f(acc[mt][reg]) * wqh;
    }
    #pragma unroll
    for (int m = 1; m <= 8; m <<= 1)
      #pragma unroll
      for (int i = 0; i < 16; ++i)
        part[i] += __shfl_xor(part[i], m);
    if (r == 0) {
      #pragma unroll
      for (int mt = 0; mt < 4; ++mt)
        #pragma unroll
        for (int reg = 0; reg < 4; ++reg)
          sAPart[wv][mt * 16 + q * 4 + reg] = part[mt * 4 + reg];
    }
  }
  __syncthreads();
  if (t < 64) {
    sAlpha[t] = (sAPart[0][t] + sAPart[1][t] + sAPart[2][t] + sAPart[3][t])
              * (float)sMaskArr[t];
  }
  __syncthreads();
  if (t < HH) {
    float acc = 0.0f;
    #pragma unroll
    for (int l = 0; l < 64; ++l)
      acc = fmaf(sAlpha[l], b2f(sH[sAliasRow[l] * SH_STR + t]), acc);
    sGlob[t] = acc;
  }
  __syncthreads();
  if (t < HH) {
    const float4* w34 = reinterpret_cast<const float4*>(w3 + (size_t)t * 256);
    const uint2*  lr  = reinterpret_cast<const uint2*>(&sH[lastRow * SH_STR]);
    float a0 = b3[t], a1 = 0.f, a2v = 0.f, a3 = 0.f;
    #pragma unroll 8
    for (int j = 0; j < 32; ++j) {
      float4 w = w34[j]; uint2 v = lr[j];
      a0  = fmaf(b2f_lo(v.x), w.x, a0);  a1 = fmaf(b2f_hi(v.x), w.y, a1);
      a2v = fmaf(b2f_lo(v.y), w.z, a2v); a3 = fmaf(b2f_hi(v.y), w.w, a3);
    }
    const float4* w34b = w34 + 32;
    #pragma unroll 8
    for (int j = 0; j < 32; ++j) {
      float4 w = w34b[j];
      a0  = fmaf(sGlob[4*j+0], w.x, a0);  a1 = fmaf(sGlob[4*j+1], w.y, a1);
      a2v = fmaf(sGlob[4*j+2], w.z, a2v); a3 = fmaf(sGlob[4*j+3], w.w, a3);
    }
    out[b * HH + t] = (a0 + a1) + (a2v + a3);
  }
}

extern "C" void kernel_launch(void* const* d_in, const int* in_sizes, int n_in,
                              void* d_out, int out_size, void* d_ws, size_t ws_size,
                              hipStream_t stream) {
  const float* A          = (const float*)d_in[0];
  const int*   items      = (const int*)  d_in[1];
  const int*   mask       = (const int*)  d_in[2];
  const int*   alias_in   = (const int*)  d_in[3];
  const float* emb        = (const float*)d_in[4];
  const float* w_in       = (const float*)d_in[5];
  const float* b_in       = (const float*)d_in[6];
  const float* w_out      = (const float*)d_in[7];
  const float* b_out      = (const float*)d_in[8];
  const float* b_iah      = (const float*)d_in[9];
  const float* b_oah      = (const float*)d_in[10];
  const float* wi         = (const float*)d_in[11];
  const float* bi         = (const float*)d_in[12];
  const float* wh         = (const float*)d_in[13];
  const float* bh         = (const float*)d_in[14];
  const float* w1         = (const float*)d_in[15];
  const float* b1         = (const float*)d_in[16];
  const float* w2         = (const float*)d_in[17];
  const float* b2         = (const float*)d_in[18];
  const float* wq         = (const float*)d_in[19];
  const float* w3         = (const float*)d_in[20];
  const float* b3         = (const float*)d_in[21];
  float* out = (float*)d_out;
  uint16_t* wsp = (uint16_t*)d_ws;

  hipLaunchKernelGGL(pack_weights, dim3((N_FRAGS + 255) / 256), dim3(256), 0, stream,
                     w_in, w_out, wi, wh, w2, wsp);
  hipLaunchKernelGGL(srgnn_kernel, dim3(NB), dim3(BDIM), 0, stream,
                     A, items, mask, alias_in, emb,
                     b_in, b_out, b_iah, b_oah, bi, bh,
                     w1, b1, b2, wq, w3, b3, wsp, out);
}

// Round 8
// 257.504 us; speedup vs baseline: 113.4700x; 1.1124x over previous
//
#include <hip/hip_runtime.h>
#include <stdint.h>

// SR-GNN fused, R8: P3 split into two u-passes (64 accs instead of 128) to cut
// register pressure below the 3-waves/SIMD threshold (~170). R7 diagnosis:
// occupancy pinned at ~22% (2 blocks/CU) by VGPR+AGPR, not LDS; latency-bound
// kernel wall scales ~1/resident-blocks. Weights stay pre-packed in d_ws.

#define BDIM 256
#define NB   1024
#define NN   64
#define HH   128
#define SH_STR 136   // u16 stride; 272B rows
#define SX_STR 264   // u16 stride; 528B rows

// d_ws fragment-layout offsets (u16 units)
#define OFS_WIN  0         // w_in : 8 tr x 4 kc x 64 lanes x 8  = 16384
#define OFS_WOUT 16384     // w_out: 16384
#define OFS_WI   32768     // wi   : 24 tr x 8 kc x 64 x 8       = 98304
#define OFS_WH   131072    // wh   : 24 tr x 4 kc x 64 x 8       = 49152
#define OFS_W2   180224    // w2   : 8 tr x 4 kc x 64 x 8        = 16384
#define N_FRAGS  24576     // total frags (16B each) = 384 KB

typedef short v8s __attribute__((ext_vector_type(8)));
typedef float v4f __attribute__((ext_vector_type(4)));

__device__ __forceinline__ float b2f_lo(uint32_t u){
  union { uint32_t u; float f; } v; v.u = u << 16; return v.f;
}
__device__ __forceinline__ float b2f_hi(uint32_t u){
  union { uint32_t u; float f; } v; v.u = u & 0xffff0000u; return v.f;
}
__device__ __forceinline__ uint16_t f2b(float f){   // RNE
  union { float f; uint32_t u; } v; v.f = f;
  uint32_t r = v.u + 0x7fffu + ((v.u >> 16) & 1u);
  return (uint16_t)(r >> 16);
}
__device__ __forceinline__ float b2f(uint16_t s){
  union { uint32_t u; float f; } v; v.u = ((uint32_t)s) << 16; return v.f;
}
__device__ __forceinline__ float sig_f(float x){ return 1.0f / (1.0f + __expf(-x)); }
__device__ __forceinline__ float tanh_f(float x){ return 1.0f - 2.0f / (__expf(2.0f*x) + 1.0f); }

// round-half-up f32->bf16 pack of two floats (a=lo16, b=hi16)
__device__ __forceinline__ uint32_t pack2bf(float a, float b){
  union { float f; uint32_t u; } ua, ub; ua.f = a; ub.f = b;
  return __builtin_amdgcn_perm(ub.u + 0x8000u, ua.u + 0x8000u, 0x07060302u);
}

__device__ __forceinline__ v8s pack8(const float* __restrict__ p){
  float4 f0 = *reinterpret_cast<const float4*>(p);
  float4 f1 = *reinterpret_cast<const float4*>(p + 4);
  union { uint32_t u[4]; v8s v; } o;
  o.u[0] = pack2bf(f0.x, f0.y);
  o.u[1] = pack2bf(f0.z, f0.w);
  o.u[2] = pack2bf(f1.x, f1.y);
  o.u[3] = pack2bf(f1.z, f1.w);
  return o.v;
}

// A-frag from LDS bf16 row-major
__device__ __forceinline__ v8s ldsA(const uint16_t* buf, int stride,
                                    int row_base, int k_base, int r, int q){
  return *reinterpret_cast<const v8s*>(&buf[(row_base + r) * stride + k_base + q * 8]);
}

// pre-packed B-frag: one coalesced 16B load
__device__ __forceinline__ v8s ldfrag(const uint16_t* __restrict__ ws,
                                      int base, int tile, int lane){
  return *reinterpret_cast<const v8s*>(ws + base + (((size_t)tile * 64 + lane) << 3));
}

#define MFMA(a, b, c) __builtin_amdgcn_mfma_f32_16x16x32_bf16((a), (b), (c), 0, 0, 0)

// ---------------- pre-pass: pack weights into frag layout ----------------
__global__ __launch_bounds__(256) void pack_weights(
    const float* __restrict__ w_in, const float* __restrict__ w_out,
    const float* __restrict__ wi,   const float* __restrict__ wh,
    const float* __restrict__ w2,   uint16_t* __restrict__ ws)
{
  int gid = blockIdx.x * blockDim.x + threadIdx.x;
  if (gid >= N_FRAGS) return;
  const float* W; int C; int fi; int base;
  if (gid < 2048)       { W = w_in;  C = 128; fi = gid;         base = OFS_WIN; }
  else if (gid < 4096)  { W = w_out; C = 128; fi = gid - 2048;  base = OFS_WOUT; }
  else if (gid < 16384) { W = wi;    C = 256; fi = gid - 4096;  base = OFS_WI; }
  else if (gid < 22528) { W = wh;    C = 128; fi = gid - 16384; base = OFS_WH; }
  else                  { W = w2;    C = 128; fi = gid - 22528; base = OFS_W2; }
  int lane = fi & 63;
  int tile = fi >> 6;            // tr * (C/32) + kc
  int tc   = C >> 5;
  int tr   = tile / tc, kc = tile - tr * tc;
  int r = lane & 15, q = lane >> 4;
  const float* p = W + (size_t)(tr * 16 + r) * C + kc * 32 + q * 8;
  *reinterpret_cast<v8s*>(ws + base + ((size_t)fi << 3)) = pack8(p);
}

// ---------------- main kernel ----------------
__global__ __launch_bounds__(BDIM, 3) void srgnn_kernel(
    const float* __restrict__ A,
    const int*   __restrict__ items,
    const int*   __restrict__ mask,
    const int*   __restrict__ alias_input,
    const float* __restrict__ emb,
    const float* __restrict__ b_in,  const float* __restrict__ b_out,
    const float* __restrict__ b_iah, const float* __restrict__ b_oah,
    const float* __restrict__ bi,    const float* __restrict__ bh,
    const float* __restrict__ w1,    const float* __restrict__ b1,
    const float* __restrict__ b2,
    const float* __restrict__ wq,
    const float* __restrict__ w3,    const float* __restrict__ b3,
    const uint16_t* __restrict__ ws,
    float* __restrict__ out)
{
  __shared__ __align__(16) uint16_t sH[NN * SH_STR];   // hidden bf16, 17.0 KB
  __shared__ __align__(16) uint16_t sX[NN * SX_STR];   // h_in|h_out -> ie, 33.0 KB
  __shared__ float sQ1[128], sGlob[128], sAPart[4][64], sAlpha[64];
  __shared__ int   sAliasRow[64], sMaskArr[64];

  const int t    = threadIdx.x;
  const int b    = blockIdx.x;
  const int lane = t & 63;
  const int wv   = __builtin_amdgcn_readfirstlane(t >> 6);
  const int r    = lane & 15;
  const int q    = lane >> 4;

  // ---------- P0: embeddings + alias/mask; hoisted A-fragments ----------
  {
    const int* itb = items + b * NN;
    for (int j = t; j < NN * HH; j += BDIM) {
      int n = j >> 7, k = j & 127;
      sH[n * SH_STR + k] = f2b(emb[(size_t)itb[n] * HH + k]);
    }
    if (t < 64) {
      sAliasRow[t] = alias_input[b * 64 + t];
      sMaskArr[t]  = mask[b * 64 + t];
    }
  }

  // A-fragments: step-invariant, load+pack once (wave's half of A)
  v8s a2[4][2];
  {
    const int half = wv >> 1;
    #pragma unroll
    for (int mt = 0; mt < 4; ++mt)
      #pragma unroll
      for (int kk = 0; kk < 2; ++kk)
        a2[mt][kk] = pack8(A + (size_t)(b * NN + mt * 16 + r) * (2 * NN)
                             + half * 64 + kk * 32 + q * 8);
  }
  __syncthreads();

  for (int step = 0; step < 2; ++step) {
    // ---------- P1 (MFMA): sX[n][c] = bias[c] + sum_k H[n][k]*W[c][k] ----------
    {
      v8s a[4][4];
      #pragma unroll
      for (int mt = 0; mt < 4; ++mt)
        #pragma unroll
        for (int kk = 0; kk < 4; ++kk)
          a[mt][kk] = ldsA(sH, SH_STR, mt * 16, kk * 32, r, q);

      const int    wbase = (wv < 2) ? OFS_WIN : OFS_WOUT;
      const float* bsel  = (wv < 2) ? b_in : b_out;
      const int    ntofs = (wv < 2) ? 0 : 8;
      #pragma unroll 2
      for (int i = 0; i < 4; ++i) {
        int nt = wv * 4 + i;
        int tr = nt - ntofs;
        int c  = nt * 16 + r;
        float bini = bsel[tr * 16 + r];
        v4f acc0 = {bini, bini, bini, bini}, acc1 = acc0, acc2 = acc0, acc3 = acc0;
        #pragma unroll
        for (int kk = 0; kk < 4; ++kk) {
          v8s bf = ldfrag(ws, wbase, tr * 4 + kk, lane);
          acc0 = MFMA(a[0][kk], bf, acc0);
          acc1 = MFMA(a[1][kk], bf, acc1);
          acc2 = MFMA(a[2][kk], bf, acc2);
          acc3 = MFMA(a[3][kk], bf, acc3);
        }
        #pragma unroll
        for (int reg = 0; reg < 4; ++reg) {
          sX[(0  + q * 4 + reg) * SX_STR + c] = f2b(acc0[reg]);
          sX[(16 + q * 4 + reg) * SX_STR + c] = f2b(acc1[reg]);
          sX[(32 + q * 4 + reg) * SX_STR + c] = f2b(acc2[reg]);
          sX[(48 + q * 4 + reg) * SX_STR + c] = f2b(acc3[reg]);
        }
      }
    }
    // no barrier: each wave reads back only its own columns in P2

    // ---------- P2 (MFMA): ie[n][c] = bias[c] + sum_m Adj[n][m]*X[m][c] ----
    {
      const float* bsel2 = (wv < 2) ? b_iah : b_oah;
      const int    wofs2 = (wv < 2) ? 0 : 128;
      #pragma unroll 1
      for (int i = 0; i < 4; ++i) {
        int nt = wv * 4 + i;
        int c  = nt * 16 + r;
        v8s b0, b1f;
        #pragma unroll
        for (int j = 0; j < 8; ++j) {
          b0[j]  = (short)sX[(q * 8 + j) * SX_STR + c];
          b1f[j] = (short)sX[(32 + q * 8 + j) * SX_STR + c];
        }
        float bini = bsel2[c - wofs2];
        v4f acc0 = {bini, bini, bini, bini}, acc1 = acc0, acc2 = acc0, acc3 = acc0;
        acc0 = MFMA(a2[0][0], b0, acc0); acc0 = MFMA(a2[0][1], b1f, acc0);
        acc1 = MFMA(a2[1][0], b0, acc1); acc1 = MFMA(a2[1][1], b1f, acc1);
        acc2 = MFMA(a2[2][0], b0, acc2); acc2 = MFMA(a2[2][1], b1f, acc2);
        acc3 = MFMA(a2[3][0], b0, acc3); acc3 = MFMA(a2[3][1], b1f, acc3);
        #pragma unroll
        for (int reg = 0; reg < 4; ++reg) {
          sX[(0  + q * 4 + reg) * SX_STR + c] = f2b(acc0[reg]);
          sX[(16 + q * 4 + reg) * SX_STR + c] = f2b(acc1[reg]);
          sX[(32 + q * 4 + reg) * SX_STR + c] = f2b(acc2[reg]);
          sX[(48 + q * 4 + reg) * SX_STR + c] = f2b(acc3[reg]);
        }
      }
    }
    __syncthreads();

    // ---------- P3 (MFMA): gates, two u-passes of 16 h-cols (64 accs live) ----
    {
      const int h0 = wv * 32;
      uint32_t nhpk[2][8];   // stashed new-hidden bf16 pairs (reg 2k|2k+1)

      #pragma unroll 1
      for (int u = 0; u < 2; ++u) {
        int h = h0 + u * 16 + r;
        float vR  = bi[h] + bh[h];
        float vI  = bi[128 + h] + bh[128 + h];
        float vNi = bi[256 + h];
        float vNh = bh[256 + h];
        v4f aR[4], aI[4], aNi[4], aNh[4];
        #pragma unroll
        for (int mt = 0; mt < 4; ++mt) {
          aR[mt]  = (v4f){vR, vR, vR, vR};
          aI[mt]  = (v4f){vI, vI, vI, vI};
          aNi[mt] = (v4f){vNi, vNi, vNi, vNi};
          aNh[mt] = (v4f){vNh, vNh, vNh, vNh};
        }
        const int trb = wv * 2 + u;
        // gi: IE[64x256] @ wi^T
        #pragma unroll 2
        for (int kk = 0; kk < 8; ++kk) {
          v8s af0 = ldsA(sX, SX_STR, 0,  kk * 32, r, q);
          v8s af1 = ldsA(sX, SX_STR, 16, kk * 32, r, q);
          v8s af2 = ldsA(sX, SX_STR, 32, kk * 32, r, q);
          v8s af3 = ldsA(sX, SX_STR, 48, kk * 32, r, q);
          v8s bR = ldfrag(ws, OFS_WI, (0 * 8 + trb) * 8 + kk, lane);
          v8s bI = ldfrag(ws, OFS_WI, (8 + trb) * 8 + kk, lane);
          v8s bN = ldfrag(ws, OFS_WI, (16 + trb) * 8 + kk, lane);
          aR[0]  = MFMA(af0, bR, aR[0]);  aR[1]  = MFMA(af1, bR, aR[1]);
          aR[2]  = MFMA(af2, bR, aR[2]);  aR[3]  = MFMA(af3, bR, aR[3]);
          aI[0]  = MFMA(af0, bI, aI[0]);  aI[1]  = MFMA(af1, bI, aI[1]);
          aI[2]  = MFMA(af2, bI, aI[2]);  aI[3]  = MFMA(af3, bI, aI[3]);
          aNi[0] = MFMA(af0, bN, aNi[0]); aNi[1] = MFMA(af1, bN, aNi[1]);
          aNi[2] = MFMA(af2, bN, aNi[2]); aNi[3] = MFMA(af3, bN, aNi[3]);
        }
        // gh: H[64x128] @ wh^T
        #pragma unroll 2
        for (int kk = 0; kk < 4; ++kk) {
          v8s af0 = ldsA(sH, SH_STR, 0,  kk * 32, r, q);
          v8s af1 = ldsA(sH, SH_STR, 16, kk * 32, r, q);
          v8s af2 = ldsA(sH, SH_STR, 32, kk * 32, r, q);
          v8s af3 = ldsA(sH, SH_STR, 48, kk * 32, r, q);
          v8s bR = ldfrag(ws, OFS_WH, (0 * 8 + trb) * 4 + kk, lane);
          v8s bI = ldfrag(ws, OFS_WH, (8 + trb) * 4 + kk, lane);
          v8s bN = ldfrag(ws, OFS_WH, (16 + trb) * 4 + kk, lane);
          aR[0]  = MFMA(af0, bR, aR[0]);  aR[1]  = MFMA(af1, bR, aR[1]);
          aR[2]  = MFMA(af2, bR, aR[2]);  aR[3]  = MFMA(af3, bR, aR[3]);
          aI[0]  = MFMA(af0, bI, aI[0]);  aI[1]  = MFMA(af1, bI, aI[1]);
          aI[2]  = MFMA(af2, bI, aI[2]);  aI[3]  = MFMA(af3, bI, aI[3]);
          aNh[0] = MFMA(af0, bN, aNh[0]); aNh[1] = MFMA(af1, bN, aNh[1]);
          aNh[2] = MFMA(af2, bN, aNh[2]); aNh[3] = MFMA(af3, bN, aNh[3]);
        }
        // epilogue-compute: stash new hidden as packed bf16 (no LDS write yet)
        #pragma unroll
        for (int mt = 0; mt < 4; ++mt) {
          #pragma unroll
          for (int rp = 0; rp < 2; ++rp) {
            uint32_t pk = 0;
            #pragma unroll
            for (int e = 0; e < 2; ++e) {
              int reg = rp * 2 + e;
              int row = mt * 16 + q * 4 + reg;
              float z  = sig_f(aI[mt][reg]);
              float rr = sig_f(aR[mt][reg]);
              float gg = tanh_f(fmaf(rr, aNh[mt][reg], aNi[mt][reg]));
              float hp = b2f(sH[row * SH_STR + h]);
              pk |= (uint32_t)f2b(fmaf(z, gg - hp, hp)) << (16 * e);
            }
            nhpk[u][mt * 2 + rp] = pk;
          }
        }
      }
      __syncthreads();   // all waves done reading sX/sH before sH overwrite

      #pragma unroll
      for (int u = 0; u < 2; ++u) {
        int h = h0 + u * 16 + r;
        #pragma unroll
        for (int mt = 0; mt < 4; ++mt)
          #pragma unroll
          for (int rp = 0; rp < 2; ++rp) {
            uint32_t pk = nhpk[u][mt * 2 + rp];
            int row = mt * 16 + q * 4 + rp * 2;
            sH[row * SH_STR + h]       = (uint16_t)(pk & 0xffff);
            sH[(row + 1) * SH_STR + h] = (uint16_t)(pk >> 16);
          }
      }
    }
    __syncthreads();
  }

  // ---------- P4: attention readout ----------
  int msum = 0;
  #pragma unroll
  for (int l = 0; l < 64; ++l) msum += sMaskArr[l];
  const int lastRow = sAliasRow[msum - 1];

  // q1[t] = b1[t] + dot(local, w1[t]) — fp32 weights direct
  if (t < HH) {
    const float4* w14 = reinterpret_cast<const float4*>(w1 + (size_t)t * HH);
    const uint2*  lr  = reinterpret_cast<const uint2*>(&sH[lastRow * SH_STR]);
    float a0 = b1[t], a1 = 0.f, a2v = 0.f, a3 = 0.f;
    #pragma unroll 8
    for (int j = 0; j < 32; ++j) {
      float4 w = w14[j]; uint2 v = lr[j];
      a0  = fmaf(b2f_lo(v.x), w.x, a0);  a1 = fmaf(b2f_hi(v.x), w.y, a1);
      a2v = fmaf(b2f_lo(v.y), w.z, a2v); a3 = fmaf(b2f_hi(v.y), w.w, a3);
    }
    sQ1[t] = (a0 + a1) + (a2v + a3);
  }
  __syncthreads();

  // alpha (MFMA): wave wv covers h in [wv*32, wv*32+32)
  {
    v8s a[4][4];
    #pragma unroll
    for (int mt = 0; mt < 4; ++mt) {
      int row = sAliasRow[mt * 16 + r];
      #pragma unroll
      for (int kk = 0; kk < 4; ++kk)
        a[mt][kk] = *reinterpret_cast<const v8s*>(&sH[row * SH_STR + kk * 32 + q * 8]);
    }
    float part[16];
    #pragma unroll
    for (int i = 0; i < 16; ++i) part[i] = 0.f;
    #pragma unroll
    for (int u = 0; u < 2; ++u) {
      int h = wv * 32 + u * 16 + r;
      float binit = sQ1[h] + b2[h];
      v4f acc[4];
      #pragma unroll
      for (int mt = 0; mt < 4; ++mt) acc[mt] = (v4f){binit, binit, binit, binit};
      #pragma unroll
      for (int kk = 0; kk < 4; ++kk) {
        v8s bf = ldfrag(ws, OFS_W2, (wv * 2 + u) * 4 + kk, lane);
        acc[0] = MFMA(a[0][kk], bf, acc[0]);
        acc[1] = MFMA(a[1][kk], bf, acc[1]);
        acc[2] = MFMA(a[2][kk], bf, acc[2]);
        acc[3] = MFMA(a[3][kk], bf, acc[3]);
      }
      float wqh = wq[h];
      #pragma unroll
      for (int mt = 0; mt < 4; ++mt)
        #pragma unroll
        for (int reg = 0; reg < 4; ++reg)
          part[mt * 4 + reg] += sig_f(acc[mt][reg]) * wqh;
    }
    #pragma unroll
    for (int m = 1; m <= 8; m <<= 1)
      #pragma unroll
      for (int i = 0; i < 16; ++i)
        part[i] += __shfl_xor(part[i], m);
    if (r == 0) {
      #pragma unroll
      for (int mt = 0; mt < 4; ++mt)
        #pragma unroll
        for (int reg = 0; reg < 4; ++reg)
          sAPart[wv][mt * 16 + q * 4 + reg] = part[mt * 4 + reg];
    }
  }
  __syncthreads();
  if (t < 64) {
    sAlpha[t] = (sAPart[0][t] + sAPart[1][t] + sAPart[2][t] + sAPart[3][t])
              * (float)sMaskArr[t];
  }
  __syncthreads();
  if (t < HH) {
    float acc = 0.0f;
    #pragma unroll
    for (int l = 0; l < 64; ++l)
      acc = fmaf(sAlpha[l], b2f(sH[sAliasRow[l] * SH_STR + t]), acc);
    sGlob[t] = acc;
  }
  __syncthreads();
  if (t < HH) {
    const float4* w34 = reinterpret_cast<const float4*>(w3 + (size_t)t * 256);
    const uint2*  lr  = reinterpret_cast<const uint2*>(&sH[lastRow * SH_STR]);
    float a0 = b3[t], a1 = 0.f, a2v = 0.f, a3 = 0.f;
    #pragma unroll 8
    for (int j = 0; j < 32; ++j) {
      float4 w = w34[j]; uint2 v = lr[j];
      a0  = fmaf(b2f_lo(v.x), w.x, a0);  a1 = fmaf(b2f_hi(v.x), w.y, a1);
      a2v = fmaf(b2f_lo(v.y), w.z, a2v); a3 = fmaf(b2f_hi(v.y), w.w, a3);
    }
    const float4* w34b = w34 + 32;
    #pragma unroll 8
    for (int j = 0; j < 32; ++j) {
      float4 w = w34b[j];
      a0  = fmaf(sGlob[4*j+0], w.x, a0);  a1 = fmaf(sGlob[4*j+1], w.y, a1);
      a2v = fmaf(sGlob[4*j+2], w.z, a2v); a3 = fmaf(sGlob[4*j+3], w.w, a3);
    }
    out[b * HH + t] = (a0 + a1) + (a2v + a3);
  }
}

extern "C" void kernel_launch(void* const* d_in, const int* in_sizes, int n_in,
                              void* d_out, int out_size, void* d_ws, size_t ws_size,
                              hipStream_t stream) {
  const float* A          = (const float*)d_in[0];
  const int*   items      = (const int*)  d_in[1];
  const int*   mask       = (const int*)  d_in[2];
  const int*   alias_in   = (const int*)  d_in[3];
  const float* emb        = (const float*)d_in[4];
  const float* w_in       = (const float*)d_in[5];
  const float* b_in       = (const float*)d_in[6];
  const float* w_out      = (const float*)d_in[7];
  const float* b_out      = (const float*)d_in[8];
  const float* b_iah      = (const float*)d_in[9];
  const float* b_oah      = (const float*)d_in[10];
  const float* wi         = (const float*)d_in[11];
  const float* bi         = (const float*)d_in[12];
  const float* wh         = (const float*)d_in[13];
  const float* bh         = (const float*)d_in[14];
  const float* w1         = (const float*)d_in[15];
  const float* b1         = (const float*)d_in[16];
  const float* w2         = (const float*)d_in[17];
  const float* b2         = (const float*)d_in[18];
  const float* wq         = (const float*)d_in[19];
  const float* w3         = (const float*)d_in[20];
  const float* b3         = (const float*)d_in[21];
  float* out = (float*)d_out;
  uint16_t* wsp = (uint16_t*)d_ws;

  hipLaunchKernelGGL(pack_weights, dim3((N_FRAGS + 255) / 256), dim3(256), 0, stream,
                     w_in, w_out, wi, wh, w2, wsp);
  hipLaunchKernelGGL(srgnn_kernel, dim3(NB), dim3(BDIM), 0, stream,
                     A, items, mask, alias_in, emb,
                     b_in, b_out, b_iah, b_oah, bi, bh,
                     w1, b1, b2, wq, w3, b3, wsp, out);
}